// Round 2
// baseline (291.822 us; speedup 1.0000x reference)
//
#include <hip/hip_runtime.h>

// ============================================================================
// ExtraAttention on MI355X (gfx950), bf16 MFMA pipeline.
// Stages: cvt(x,M) -> transpose_cvt(W*) -> GEMM QKV/EKV -> build_kv (K,V^T
//         rearrange) -> flash attention (S^T trick, causal tile skip) ->
//         GEMM proj (fp32 out)
// Dims: B=4 S=1024 P=128 NX=1024 H=16 dh=64 T=1152
// ============================================================================

typedef __attribute__((ext_vector_type(8))) short bf16x8;
typedef __attribute__((ext_vector_type(4))) float f32x4;

#define MFMA16(a, b, c) __builtin_amdgcn_mfma_f32_16x16x32_bf16((a), (b), (c), 0, 0, 0)

static __device__ __forceinline__ unsigned short f2bf(float f) {
    union { float f; unsigned int u; } v; v.f = f;
    unsigned int u = v.u;
    return (unsigned short)((u + 0x7fffu + ((u >> 16) & 1u)) >> 16);  // RNE
}

// ---------------------------------------------------------------------------
// fp32 -> bf16, 4 elems/thread
__global__ void cvt_f32_bf16(const float* __restrict__ in, unsigned short* __restrict__ out, int n4) {
    int i = blockIdx.x * 256 + threadIdx.x;
    if (i >= n4) return;
    float4 v = ((const float4*)in)[i];
    ushort4 o;
    o.x = f2bf(v.x); o.y = f2bf(v.y); o.z = f2bf(v.z); o.w = f2bf(v.w);
    ((ushort4*)out)[i] = o;
}

// ---------------------------------------------------------------------------
// W [K][N] fp32 row-major -> Wt [N][K] bf16 row-major (32x32 LDS tiles)
__global__ void transpose_cvt(const float* __restrict__ W, unsigned short* __restrict__ Wt,
                              int K, int N) {
    __shared__ float tile[32][33];
    int n0 = blockIdx.x * 32, k0 = blockIdx.y * 32;
    int tx = threadIdx.x & 31, ty = threadIdx.x >> 5;  // 256 thr: ty 0..7
    #pragma unroll
    for (int r = ty; r < 32; r += 8) tile[r][tx] = W[(size_t)(k0 + r) * N + n0 + tx];
    __syncthreads();
    #pragma unroll
    for (int r = ty; r < 32; r += 8) Wt[(size_t)(n0 + r) * K + k0 + tx] = f2bf(tile[tx][r]);
}

// ---------------------------------------------------------------------------
// Fused additive bias over keys, pre-scaled by log2(e): biasT[b][t]
__global__ void build_bias(const float* __restrict__ Mmask, const float* __restrict__ amask,
                           float* __restrict__ biasT) {
    int i = blockIdx.x * 256 + threadIdx.x;
    if (i >= 4 * 1152) return;
    int b = i / 1152, t = i % 1152;
    float v = (t < 128) ? (Mmask[b * 128 + t] - 1.f) * 10000.f : amask[b * 1024 + t - 128];
    biasT[i] = v * 1.4426950408889634f;
}

// ---------------------------------------------------------------------------
// Rearrange K/V: Kc[b*h][t][64] and Vt[b*h][64][t] from EKV (t<128) / QKV.
// One block per (b,h,64-t chunk); V transposed through LDS.
__global__ __launch_bounds__(256) void build_kv(const unsigned short* __restrict__ QKV,
                                                const unsigned short* __restrict__ EKV,
                                                unsigned short* __restrict__ Kc,
                                                unsigned short* __restrict__ Vt) {
    __shared__ unsigned short vt[64][72];
    const int tid = threadIdx.x;
    const int blk = blockIdx.x;            // B*H*18
    const int tc = blk % 18, bh = blk / 18;
    const int h = bh & 15, b = bh >> 4;
    const int row = tid >> 2, c = (tid & 3) * 16;
    const int tg = tc * 64 + row;
    const unsigned short* src;
    if (tg < 128) src = EKV + (size_t)(b * 128 + tg) * 2048 + h * 64 + c;
    else          src = QKV + (size_t)(b * 1024 + tg - 128) * 3072 + 1024 + h * 64 + c;
    bf16x8 ka = *(const bf16x8*)src;
    bf16x8 kb = *(const bf16x8*)(src + 8);
    bf16x8 va = *(const bf16x8*)(src + 1024);
    bf16x8 vb = *(const bf16x8*)(src + 1032);
    unsigned short* kd = Kc + (size_t)bh * 73728 + (size_t)tg * 64 + c;
    *(bf16x8*)kd = ka;
    *(bf16x8*)(kd + 8) = kb;
    *(bf16x8*)&vt[row][c] = va;
    *(bf16x8*)&vt[row][c + 8] = vb;
    __syncthreads();
    bf16x8 o0, o1;
    #pragma unroll
    for (int j = 0; j < 8; j++) { o0[j] = vt[c + j][row]; o1[j] = vt[c + 8 + j][row]; }
    unsigned short* vd = Vt + (size_t)bh * 73728 + (size_t)row * 1152 + tc * 64 + c;
    *(bf16x8*)vd = o0;
    *(bf16x8*)(vd + 8) = o1;
}

// ---------------------------------------------------------------------------
// C[M][N] = A[M][K](bf16) x Bt[N][K](bf16)^T + bias[N]
// 128x128 block tile, BK=32, 4 waves (each 64x64 = 4x4 MFMA 16x16x32 tiles).
template <int STORE_BF16>
__global__ __launch_bounds__(256) void gemm_bt(const unsigned short* __restrict__ A,
                                               const unsigned short* __restrict__ Bt,
                                               const float* __restrict__ bias,
                                               void* __restrict__ C, int M, int N, int K) {
    __shared__ unsigned short As[128 * 40];
    __shared__ unsigned short Bs[128 * 40];
    const int tid = threadIdx.x;
    const int lane = tid & 63, wave = tid >> 6;
    const int quad = lane >> 4, l16 = lane & 15;
    const int wm = (wave & 1) * 64, wn = (wave >> 1) * 64;
    const int bm = blockIdx.x, bn = blockIdx.y;
    const int srow = tid >> 1, scol = (tid & 1) * 16;
    const unsigned short* Ag = A + (size_t)(bm * 128 + srow) * K + scol;
    const unsigned short* Bg = Bt + (size_t)(bn * 128 + srow) * K + scol;

    f32x4 acc[4][4] = {};
    for (int k0 = 0; k0 < K; k0 += 32) {
        bf16x8 a0 = *(const bf16x8*)(Ag + k0);
        bf16x8 a1 = *(const bf16x8*)(Ag + k0 + 8);
        bf16x8 b0 = *(const bf16x8*)(Bg + k0);
        bf16x8 b1 = *(const bf16x8*)(Bg + k0 + 8);
        __syncthreads();
        *(bf16x8*)&As[srow * 40 + scol] = a0;
        *(bf16x8*)&As[srow * 40 + scol + 8] = a1;
        *(bf16x8*)&Bs[srow * 40 + scol] = b0;
        *(bf16x8*)&Bs[srow * 40 + scol + 8] = b1;
        __syncthreads();
        bf16x8 af[4], bf[4];
        #pragma unroll
        for (int i = 0; i < 4; i++) af[i] = *(const bf16x8*)&As[(wm + i * 16 + l16) * 40 + quad * 8];
        #pragma unroll
        for (int j = 0; j < 4; j++) bf[j] = *(const bf16x8*)&Bs[(wn + j * 16 + l16) * 40 + quad * 8];
        #pragma unroll
        for (int i = 0; i < 4; i++)
            #pragma unroll
            for (int j = 0; j < 4; j++)
                acc[i][j] = MFMA16(af[i], bf[j], acc[i][j]);
    }
    float bj[4];
    #pragma unroll
    for (int j = 0; j < 4; j++) bj[j] = bias[bn * 128 + wn + j * 16 + l16];
    #pragma unroll
    for (int i = 0; i < 4; i++) {
        const int row = bm * 128 + wm + i * 16 + quad * 4;
        #pragma unroll
        for (int j = 0; j < 4; j++) {
            const int col = bn * 128 + wn + j * 16 + l16;
            #pragma unroll
            for (int r = 0; r < 4; r++) {
                float v = acc[i][j][r] + bj[j];
                if (STORE_BF16)
                    ((unsigned short*)C)[(size_t)(row + r) * N + col] = f2bf(v);
                else
                    ((float*)C)[(size_t)(row + r) * N + col] = v;
            }
        }
    }
}

// ---------------------------------------------------------------------------
// Attention v2: block = (b, h, 128 q-rows); wave owns 32 q-rows.
// K tiles of 64 t staged from Kc [t][64]; V from Vt [64][t].
// S^T = MFMA(K,Q): C-layout row=t, col=s -> P spill is contiguous ds_write_b64,
// reload is PV's A-operand layout. Causal tile skip: t < 256 + qt*128.
__global__ __launch_bounds__(256) void attn_kernel(const unsigned short* __restrict__ QKV,
                                                   const unsigned short* __restrict__ Kc,
                                                   const unsigned short* __restrict__ Vt,
                                                   const float* __restrict__ biasT,
                                                   unsigned short* __restrict__ Aout) {
    __shared__ unsigned short Ks[64 * 72];
    __shared__ unsigned short Vs[64 * 72];
    __shared__ unsigned short Ps[4][32 * 72];
    const int tid = threadIdx.x;
    const int lane = tid & 63, wave = tid >> 6;
    const int quad = lane >> 4, l16 = lane & 15;
    const int blk = blockIdx.x;                    // 512 = B*H*8
    const int qt = 7 - (blk & 7), bh = blk >> 3;   // long blocks first
    const int h = bh & 15, b = bh >> 4;
    const int qrow_w = qt * 128 + wave * 32;
    const int srow = tid >> 2, scol = (tid & 3) * 16;

    // Q fragments (B-operand for S^T; same lane layout as A-operand)
    bf16x8 qf[2][2];
    #pragma unroll
    for (int sm = 0; sm < 2; sm++)
        #pragma unroll
        for (int k2 = 0; k2 < 2; k2++)
            qf[sm][k2] = *(const bf16x8*)(QKV + (size_t)(b * 1024 + qrow_w + sm * 16 + l16) * 3072 +
                                          h * 64 + k2 * 32 + quad * 8);

    const unsigned short* Kg = Kc + (size_t)bh * 73728 + (size_t)srow * 64 + scol;
    const unsigned short* Vg = Vt + (size_t)bh * 73728 + (size_t)srow * 1152 + scol;

    f32x4 o[2][4] = {};
    float den[2] = {0.f, 0.f};
    const int tmax = 256 + qt * 128;

    for (int t0 = 0; t0 < tmax; t0 += 64) {
        bf16x8 k0 = *(const bf16x8*)(Kg + (size_t)t0 * 64);
        bf16x8 k1 = *(const bf16x8*)(Kg + (size_t)t0 * 64 + 8);
        bf16x8 v0 = *(const bf16x8*)(Vg + t0);
        bf16x8 v1 = *(const bf16x8*)(Vg + t0 + 8);
        __syncthreads();
        *(bf16x8*)&Ks[srow * 72 + scol] = k0;
        *(bf16x8*)&Ks[srow * 72 + scol + 8] = k1;
        *(bf16x8*)&Vs[srow * 72 + scol] = v0;
        *(bf16x8*)&Vs[srow * 72 + scol + 8] = v1;
        __syncthreads();
        if (t0 <= qrow_w + 159) {  // tiles with t_min > s_max+128 are fully masked
            // S^T tiles: [sm][tn], row=t (quad*4+r), col=s (l16)
            f32x4 st[2][4];
            #pragma unroll
            for (int tn = 0; tn < 4; tn++) {
                bf16x8 kf0 = *(const bf16x8*)&Ks[(tn * 16 + l16) * 72 + quad * 8];
                bf16x8 kf1 = *(const bf16x8*)&Ks[(tn * 16 + l16) * 72 + 32 + quad * 8];
                #pragma unroll
                for (int sm = 0; sm < 2; sm++) {
                    f32x4 a = {};
                    a = MFMA16(kf0, qf[sm][0], a);
                    a = MFMA16(kf1, qf[sm][1], a);
                    st[sm][tn] = a;
                }
            }
            // exp + P spill ([s][t], contiguous 4 bf16 per lane)
            #pragma unroll
            for (int sm = 0; sm < 2; sm++) {
                const int sg = qrow_w + sm * 16 + l16;
                #pragma unroll
                for (int tn = 0; tn < 4; tn++) {
                    ushort4 pk;
                    unsigned short* pp = (unsigned short*)&pk;
                    #pragma unroll
                    for (int r = 0; r < 4; r++) {
                        const int tg = t0 + tn * 16 + quad * 4 + r;
                        float p = 0.f;
                        if (tg < 128 || tg - 128 <= sg)
                            p = __builtin_amdgcn_exp2f(st[sm][tn][r] * 0.18033688011112042f +
                                                       biasT[b * 1152 + tg]);
                        den[sm] += p;
                        pp[r] = f2bf(p);
                    }
                    *(ushort4*)&Ps[wave][(sm * 16 + l16) * 72 + tn * 16 + quad * 4] = pk;
                }
            }
            // PV: o[s][d] += P[s][t] V[t][d]
            #pragma unroll
            for (int tk = 0; tk < 2; tk++) {
                bf16x8 pf0 = *(const bf16x8*)&Ps[wave][(0 * 16 + l16) * 72 + tk * 32 + quad * 8];
                bf16x8 pf1 = *(const bf16x8*)&Ps[wave][(1 * 16 + l16) * 72 + tk * 32 + quad * 8];
                #pragma unroll
                for (int dn = 0; dn < 4; dn++) {
                    bf16x8 vf = *(const bf16x8*)&Vs[(dn * 16 + l16) * 72 + tk * 32 + quad * 8];
                    o[0][dn] = MFMA16(pf0, vf, o[0][dn]);
                    o[1][dn] = MFMA16(pf1, vf, o[1][dn]);
                }
            }
        }
    }

    // den lives per lane at s = sm*16 + l16; reduce over quads (disjoint t)
    #pragma unroll
    for (int sm = 0; sm < 2; sm++) {
        den[sm] += __shfl_xor(den[sm], 16, 64);
        den[sm] += __shfl_xor(den[sm], 32, 64);
    }
    #pragma unroll
    for (int sm = 0; sm < 2; sm++) {
        #pragma unroll
        for (int r = 0; r < 4; r++) {
            const float d = __shfl(den[sm], quad * 4 + r, 64);
            const float inv = 1.f / d;
            const size_t orow = (size_t)(b * 1024 + qrow_w + sm * 16 + quad * 4 + r) * 1024 + h * 64;
            #pragma unroll
            for (int dn = 0; dn < 4; dn++)
                Aout[orow + dn * 16 + l16] = f2bf(o[sm][dn][r] * inv);
        }
    }
}

// ---------------------------------------------------------------------------
extern "C" void kernel_launch(void* const* d_in, const int* in_sizes, int n_in,
                              void* d_out, int out_size, void* d_ws, size_t ws_size,
                              hipStream_t stream) {
    const float* x      = (const float*)d_in[0];
    const float* Mem    = (const float*)d_in[1];
    const float* Mmask  = (const float*)d_in[2];
    const float* amask  = (const float*)d_in[3];
    const float* W_attn = (const float*)d_in[4];
    const float* b_attn = (const float*)d_in[5];
    const float* W_mem  = (const float*)d_in[6];
    const float* b_mem  = (const float*)d_in[7];
    const float* W_proj = (const float*)d_in[8];
    const float* b_proj = (const float*)d_in[9];
    float* out = (float*)d_out;

    char* ws = (char*)d_ws;
    unsigned short* x_bf  = (unsigned short*)ws;  ws += (size_t)4096 * 1024 * 2;
    unsigned short* M_bf  = (unsigned short*)ws;  ws += (size_t)512 * 1024 * 2;
    unsigned short* Wat   = (unsigned short*)ws;  ws += (size_t)3072 * 1024 * 2;
    unsigned short* Wmt   = (unsigned short*)ws;  ws += (size_t)2048 * 1024 * 2;
    unsigned short* Wpt   = (unsigned short*)ws;  ws += (size_t)1024 * 1024 * 2;
    unsigned short* QKV   = (unsigned short*)ws;  ws += (size_t)4096 * 3072 * 2;
    unsigned short* EKV   = (unsigned short*)ws;  ws += (size_t)512 * 2048 * 2;
    unsigned short* Abuf  = (unsigned short*)ws;  ws += (size_t)4096 * 1024 * 2;
    unsigned short* Kc    = (unsigned short*)ws;  ws += (size_t)64 * 1152 * 64 * 2;
    unsigned short* Vt    = (unsigned short*)ws;  ws += (size_t)64 * 64 * 1152 * 2;
    float*          biasT = (float*)ws;           ws += (size_t)4 * 1152 * 4;
    // total ws use: ~77 MB

    cvt_f32_bf16<<<4096, 256, 0, stream>>>(x, x_bf, 4096 * 1024 / 4);
    cvt_f32_bf16<<<512, 256, 0, stream>>>(Mem, M_bf, 512 * 1024 / 4);
    transpose_cvt<<<dim3(96, 32), 256, 0, stream>>>(W_attn, Wat, 1024, 3072);
    transpose_cvt<<<dim3(64, 32), 256, 0, stream>>>(W_mem, Wmt, 1024, 2048);
    transpose_cvt<<<dim3(32, 32), 256, 0, stream>>>(W_proj, Wpt, 1024, 1024);
    build_bias<<<18, 256, 0, stream>>>(Mmask, amask, biasT);

    gemm_bt<1><<<dim3(32, 24), 256, 0, stream>>>(x_bf, Wat, b_attn, QKV, 4096, 3072, 1024);
    gemm_bt<1><<<dim3(4, 16), 256, 0, stream>>>(M_bf, Wmt, b_mem, EKV, 512, 2048, 1024);

    build_kv<<<1152, 256, 0, stream>>>(QKV, EKV, Kc, Vt);

    attn_kernel<<<512, 256, 0, stream>>>(QKV, Kc, Vt, biasT, Abuf);

    gemm_bt<0><<<dim3(32, 8), 256, 0, stream>>>(Abuf, Wpt, b_proj, out, 4096, 1024, 1024);
}

// Round 3
// 250.784 us; speedup vs baseline: 1.1636x; 1.1636x over previous
//
#include <hip/hip_runtime.h>
#include <hip/hip_bf16.h>

// ============================================================================
// ExtraAttention on MI355X (gfx950), bf16 MFMA pipeline.
// R3: barrier-free attention (direct-from-global K/V fragments, den-via-MFMA),
//     GEMMs upgraded to global_load_lds width=16 staging (m97 structure).
// Dims: B=4 S=1024 P=128 NX=1024 H=16 dh=64 T=1152
// ============================================================================

typedef __attribute__((ext_vector_type(8))) short bf16x8;
typedef __attribute__((ext_vector_type(4))) float f32x4;

#define MFMA16(a, b, c) __builtin_amdgcn_mfma_f32_16x16x32_bf16((a), (b), (c), 0, 0, 0)

#define GLOAD_LDS16(g, l)                                                  \
    __builtin_amdgcn_global_load_lds(                                      \
        (const __attribute__((address_space(1))) void*)(const void*)(g),   \
        (__attribute__((address_space(3))) void*)(void*)(l), 16, 0, 0)

static __device__ __forceinline__ unsigned short f2bf(float f) {
    union { float f; unsigned int u; } v; v.f = f;
    unsigned int u = v.u;
    return (unsigned short)((u + 0x7fffu + ((u >> 16) & 1u)) >> 16);  // RNE
}

// ---------------------------------------------------------------------------
__global__ void cvt_f32_bf16(const float* __restrict__ in, unsigned short* __restrict__ out, int n4) {
    int i = blockIdx.x * 256 + threadIdx.x;
    if (i >= n4) return;
    float4 v = ((const float4*)in)[i];
    ushort4 o;
    o.x = f2bf(v.x); o.y = f2bf(v.y); o.z = f2bf(v.z); o.w = f2bf(v.w);
    ((ushort4*)out)[i] = o;
}

// ---------------------------------------------------------------------------
__global__ void transpose_cvt(const float* __restrict__ W, unsigned short* __restrict__ Wt,
                              int K, int N) {
    __shared__ float tile[32][33];
    int n0 = blockIdx.x * 32, k0 = blockIdx.y * 32;
    int tx = threadIdx.x & 31, ty = threadIdx.x >> 5;
    #pragma unroll
    for (int r = ty; r < 32; r += 8) tile[r][tx] = W[(size_t)(k0 + r) * N + n0 + tx];
    __syncthreads();
    #pragma unroll
    for (int r = ty; r < 32; r += 8) Wt[(size_t)(n0 + r) * K + k0 + tx] = f2bf(tile[tx][r]);
}

// ---------------------------------------------------------------------------
// Fused additive key bias, pre-scaled by log2(e): biasT[b][t]
__global__ void build_bias(const float* __restrict__ Mmask, const float* __restrict__ amask,
                           float* __restrict__ biasT) {
    int i = blockIdx.x * 256 + threadIdx.x;
    if (i >= 4 * 1152) return;
    int b = i / 1152, t = i % 1152;
    float v = (t < 128) ? (Mmask[b * 128 + t] - 1.f) * 10000.f : amask[b * 1024 + t - 128];
    biasT[i] = v * 1.4426950408889634f;
}

// ---------------------------------------------------------------------------
// Rearrange K/V: Kc[b*h][t][64], Vt[b*h][64][t] from EKV (t<128) / QKV.
__global__ __launch_bounds__(256) void build_kv(const unsigned short* __restrict__ QKV,
                                                const unsigned short* __restrict__ EKV,
                                                unsigned short* __restrict__ Kc,
                                                unsigned short* __restrict__ Vt) {
    __shared__ unsigned short vt[64][72];
    const int tid = threadIdx.x;
    const int blk = blockIdx.x;            // B*H*18
    const int tc = blk % 18, bh = blk / 18;
    const int h = bh & 15, b = bh >> 4;
    const int row = tid >> 2, c = (tid & 3) * 16;
    const int tg = tc * 64 + row;
    const unsigned short* src;
    if (tg < 128) src = EKV + (size_t)(b * 128 + tg) * 2048 + h * 64 + c;
    else          src = QKV + (size_t)(b * 1024 + tg - 128) * 3072 + 1024 + h * 64 + c;
    bf16x8 ka = *(const bf16x8*)src;
    bf16x8 kb = *(const bf16x8*)(src + 8);
    bf16x8 va = *(const bf16x8*)(src + 1024);
    bf16x8 vb = *(const bf16x8*)(src + 1032);
    unsigned short* kd = Kc + (size_t)bh * 73728 + (size_t)tg * 64 + c;
    *(bf16x8*)kd = ka;
    *(bf16x8*)(kd + 8) = kb;
    *(bf16x8*)&vt[row][c] = va;
    *(bf16x8*)&vt[row][c + 8] = vb;
    __syncthreads();
    bf16x8 o0, o1;
    #pragma unroll
    for (int j = 0; j < 8; j++) { o0[j] = vt[c + j][row]; o1[j] = vt[c + 8 + j][row]; }
    unsigned short* vd = Vt + (size_t)bh * 73728 + (size_t)row * 1152 + tc * 64 + c;
    *(bf16x8*)vd = o0;
    *(bf16x8*)(vd + 8) = o1;
}

// ---------------------------------------------------------------------------
// C[M][N] = A[M][K](bf16) x Bt[N][K](bf16)^T + bias[N]
// m97 structure: 128x128 tile, BK=32, global_load_lds width=16 staging into
// unpadded [128][32] LDS, 2 barriers/iter, 4 waves x (4x4) 16x16x32 MFMA.
template <int STORE_BF16>
__global__ __launch_bounds__(256) void gemm_bt(const unsigned short* __restrict__ A,
                                               const unsigned short* __restrict__ Bt,
                                               const float* __restrict__ bias,
                                               void* __restrict__ C, int M, int N, int K) {
    __shared__ unsigned short As[128 * 32];
    __shared__ unsigned short Bs[128 * 32];
    const int tid = threadIdx.x;
    const int lane = tid & 63, wave = tid >> 6;
    const int quad = lane >> 4, l16 = lane & 15;
    const int wm = (wave & 1) * 64, wn = (wave >> 1) * 64;
    const int bm = blockIdx.x, bn = blockIdx.y;
    // staging: 16 chunks of 1KB (16 rows x 32 cols); wave w owns chunks 4w..4w+3
    const int crow = lane >> 2, ccol = (lane & 3) * 8;
    const unsigned short* Abase = A + (size_t)(bm * 128 + crow) * K + ccol;
    const unsigned short* Bbase = Bt + (size_t)(bn * 128 + crow) * K + ccol;

    f32x4 acc[4][4] = {};
    for (int k0 = 0; k0 < K; k0 += 32) {
        __syncthreads();  // all waves done reading previous tile
        #pragma unroll
        for (int cc = 0; cc < 4; cc++) {
            const int c = wave * 4 + cc;
            if (c < 8) GLOAD_LDS16(Abase + (size_t)(c * 16) * K + k0, &As[c * 512]);
            else       GLOAD_LDS16(Bbase + (size_t)((c - 8) * 16) * K + k0, &Bs[(c - 8) * 512]);
        }
        __syncthreads();  // drains vmcnt -> staged data visible
        bf16x8 af[4], bf[4];
        #pragma unroll
        for (int i = 0; i < 4; i++) af[i] = *(const bf16x8*)&As[(wm + i * 16 + l16) * 32 + quad * 8];
        #pragma unroll
        for (int j = 0; j < 4; j++) bf[j] = *(const bf16x8*)&Bs[(wn + j * 16 + l16) * 32 + quad * 8];
        #pragma unroll
        for (int i = 0; i < 4; i++)
            #pragma unroll
            for (int j = 0; j < 4; j++)
                acc[i][j] = MFMA16(af[i], bf[j], acc[i][j]);
    }
    float bj[4];
    #pragma unroll
    for (int j = 0; j < 4; j++) bj[j] = bias[bn * 128 + wn + j * 16 + l16];
    #pragma unroll
    for (int i = 0; i < 4; i++) {
        const int row = bm * 128 + wm + i * 16 + quad * 4;
        #pragma unroll
        for (int j = 0; j < 4; j++) {
            const int col = bn * 128 + wn + j * 16 + l16;
            #pragma unroll
            for (int r = 0; r < 4; r++) {
                float v = acc[i][j][r] + bj[j];
                if (STORE_BF16)
                    ((unsigned short*)C)[(size_t)(row + r) * N + col] = f2bf(v);
                else
                    ((float*)C)[(size_t)(row + r) * N + col] = v;
            }
        }
    }
}

// ---------------------------------------------------------------------------
// Attention v3: BARRIER-FREE. 128-thr blocks (2 indep waves), grid 1024.
// Wave owns 32 q-rows; K/V fragments loaded straight from global (Kc/Vt are
// L1/L2-resident, coalesced 16B/lane). Only LDS: per-wave P round-trip.
// den computed via MFMA(P, ones) -> same C-layout rows as o (no shuffles).
__global__ __launch_bounds__(128) void attn_kernel(const unsigned short* __restrict__ QKV,
                                                   const unsigned short* __restrict__ Kc,
                                                   const unsigned short* __restrict__ Vt,
                                                   const float* __restrict__ biasT,
                                                   unsigned short* __restrict__ Aout) {
    __shared__ unsigned short Ps[2][32 * 72];
    const int tid = threadIdx.x;
    const int lane = tid & 63, wave = tid >> 6;
    const int quad = lane >> 4, l16 = lane & 15;
    const int blk = blockIdx.x;                 // 1024 = 16 qg x 64 bh
    const int qg = 15 - (blk >> 6);             // longest blocks dispatched first
    const int bh = blk & 63;
    const int h = bh & 15, b = bh >> 4;
    const int qrow_w = qg * 64 + wave * 32;

    bf16x8 qf[2][2];
    #pragma unroll
    for (int sm = 0; sm < 2; sm++)
        #pragma unroll
        for (int k2 = 0; k2 < 2; k2++)
            qf[sm][k2] = *(const bf16x8*)(QKV + (size_t)(b * 1024 + qrow_w + sm * 16 + l16) * 3072 +
                                          h * 64 + k2 * 32 + quad * 8);

    const unsigned short* Kb = Kc + (size_t)bh * 73728;
    const unsigned short* Vb = Vt + (size_t)bh * 73728;
    const float* bias_b = biasT + b * 1152;

    bf16x8 ones;
    #pragma unroll
    for (int j = 0; j < 8; j++) ones[j] = (short)0x3F80;  // bf16 1.0

    f32x4 o[2][4] = {};
    f32x4 oden[2] = {};
    const int tmax = min(1152, ((qrow_w + 223) >> 6) << 6);

    for (int t0 = 0; t0 < tmax; t0 += 64) {
        // ---- direct-from-global fragment loads (all independent, deep ILP)
        bf16x8 kf[4][2], vf[2][4];
        #pragma unroll
        for (int tn = 0; tn < 4; tn++) {
            const unsigned short* kp = Kb + (size_t)(t0 + tn * 16 + l16) * 64 + quad * 8;
            kf[tn][0] = *(const bf16x8*)kp;
            kf[tn][1] = *(const bf16x8*)(kp + 32);
        }
        #pragma unroll
        for (int tk = 0; tk < 2; tk++)
            #pragma unroll
            for (int dn = 0; dn < 4; dn++)
                vf[tk][dn] = *(const bf16x8*)(Vb + (size_t)(dn * 16 + l16) * 1152 +
                                              t0 + tk * 32 + quad * 8);
        float4 bt[4];
        #pragma unroll
        for (int tn = 0; tn < 4; tn++)
            bt[tn] = *(const float4*)(bias_b + t0 + tn * 16 + quad * 4);

        const bool nomask = (t0 + 63 <= 128 + qrow_w);  // whole tile causally visible
        // ---- S^T = K x Q^T, exp, spill P to per-wave LDS ([s][t], stride 72)
        #pragma unroll
        for (int sm = 0; sm < 2; sm++) {
            const int sg = qrow_w + sm * 16 + l16;
            #pragma unroll
            for (int tn = 0; tn < 4; tn++) {
                f32x4 st = {};
                st = MFMA16(kf[tn][0], qf[sm][0], st);
                st = MFMA16(kf[tn][1], qf[sm][1], st);
                float p[4];
                #pragma unroll
                for (int r = 0; r < 4; r++) {
                    float e = __builtin_amdgcn_exp2f(st[r] * 0.18033688011112042f + bt[tn][r]);
                    if (!nomask) {
                        const int tg = t0 + tn * 16 + quad * 4 + r;
                        e = (tg < 128 || tg - 128 <= sg) ? e : 0.f;
                    }
                    p[r] = e;
                }
                union { ushort4 u; __hip_bfloat162 h2[2]; } pk;
                pk.h2[0] = __float22bfloat162_rn(float2{p[0], p[1]});
                pk.h2[1] = __float22bfloat162_rn(float2{p[2], p[3]});
                *(ushort4*)&Ps[wave][(sm * 16 + l16) * 72 + tn * 16 + quad * 4] = pk.u;
            }
        }
        // ---- PV (+ den via ones-column). Wave-internal LDS RAW: compiler waits.
        #pragma unroll
        for (int sm = 0; sm < 2; sm++) {
            #pragma unroll
            for (int tk = 0; tk < 2; tk++) {
                bf16x8 pf = *(const bf16x8*)&Ps[wave][(sm * 16 + l16) * 72 + tk * 32 + quad * 8];
                oden[sm] = MFMA16(pf, ones, oden[sm]);
                #pragma unroll
                for (int dn = 0; dn < 4; dn++)
                    o[sm][dn] = MFMA16(pf, vf[tk][dn], o[sm][dn]);
            }
        }
    }

    // ---- epilogue: o and oden share C-layout rows (s = quad*4+r)
    #pragma unroll
    for (int sm = 0; sm < 2; sm++) {
        #pragma unroll
        for (int r = 0; r < 4; r++) {
            const float inv = 1.f / oden[sm][r];
            const size_t orow = (size_t)(b * 1024 + qrow_w + sm * 16 + quad * 4 + r) * 1024 + h * 64;
            #pragma unroll
            for (int dn = 0; dn < 4; dn++)
                Aout[orow + dn * 16 + l16] = f2bf(o[sm][dn][r] * inv);
        }
    }
}

// ---------------------------------------------------------------------------
extern "C" void kernel_launch(void* const* d_in, const int* in_sizes, int n_in,
                              void* d_out, int out_size, void* d_ws, size_t ws_size,
                              hipStream_t stream) {
    const float* x      = (const float*)d_in[0];
    const float* Mem    = (const float*)d_in[1];
    const float* Mmask  = (const float*)d_in[2];
    const float* amask  = (const float*)d_in[3];
    const float* W_attn = (const float*)d_in[4];
    const float* b_attn = (const float*)d_in[5];
    const float* W_mem  = (const float*)d_in[6];
    const float* b_mem  = (const float*)d_in[7];
    const float* W_proj = (const float*)d_in[8];
    const float* b_proj = (const float*)d_in[9];
    float* out = (float*)d_out;

    char* ws = (char*)d_ws;
    unsigned short* x_bf  = (unsigned short*)ws;  ws += (size_t)4096 * 1024 * 2;
    unsigned short* M_bf  = (unsigned short*)ws;  ws += (size_t)512 * 1024 * 2;
    unsigned short* Wat   = (unsigned short*)ws;  ws += (size_t)3072 * 1024 * 2;
    unsigned short* Wmt   = (unsigned short*)ws;  ws += (size_t)2048 * 1024 * 2;
    unsigned short* Wpt   = (unsigned short*)ws;  ws += (size_t)1024 * 1024 * 2;
    unsigned short* QKV   = (unsigned short*)ws;  ws += (size_t)4096 * 3072 * 2;
    unsigned short* EKV   = (unsigned short*)ws;  ws += (size_t)512 * 2048 * 2;
    unsigned short* Abuf  = (unsigned short*)ws;  ws += (size_t)4096 * 1024 * 2;
    unsigned short* Kc    = (unsigned short*)ws;  ws += (size_t)64 * 1152 * 64 * 2;
    unsigned short* Vt    = (unsigned short*)ws;  ws += (size_t)64 * 64 * 1152 * 2;
    float*          biasT = (float*)ws;           ws += (size_t)4 * 1152 * 4;
    // total ws use: ~77 MB

    cvt_f32_bf16<<<4096, 256, 0, stream>>>(x, x_bf, 4096 * 1024 / 4);
    cvt_f32_bf16<<<512, 256, 0, stream>>>(Mem, M_bf, 512 * 1024 / 4);
    transpose_cvt<<<dim3(96, 32), 256, 0, stream>>>(W_attn, Wat, 1024, 3072);
    transpose_cvt<<<dim3(64, 32), 256, 0, stream>>>(W_mem, Wmt, 1024, 2048);
    transpose_cvt<<<dim3(32, 32), 256, 0, stream>>>(W_proj, Wpt, 1024, 1024);
    build_bias<<<18, 256, 0, stream>>>(Mmask, amask, biasT);

    gemm_bt<1><<<dim3(32, 24), 256, 0, stream>>>(x_bf, Wat, b_attn, QKV, 4096, 3072, 1024);
    gemm_bt<1><<<dim3(4, 16), 256, 0, stream>>>(M_bf, Wmt, b_mem, EKV, 512, 2048, 1024);

    build_kv<<<1152, 256, 0, stream>>>(QKV, EKV, Kc, Vt);

    attn_kernel<<<1024, 128, 0, stream>>>(QKV, Kc, Vt, biasT, Abuf);

    gemm_bt<0><<<dim3(32, 8), 256, 0, stream>>>(Abuf, Wpt, b_proj, out, 4096, 1024, 1024);
}

// Round 4
// 237.377 us; speedup vs baseline: 1.2294x; 1.0565x over previous
//
#include <hip/hip_runtime.h>
#include <hip/hip_bf16.h>

// ============================================================================
// ExtraAttention on MI355X (gfx950), bf16 MFMA pipeline.
// R4: attention = 4-wave t-split blocks (32 waves/CU of work, barrier-free
//     main loop, LDS combine); kernels consolidated 10 -> 6; QKV+EKV fused
//     into one launch; proj GEMM 128x64 tiles (512 blocks).
// Dims: B=4 S=1024 P=128 NX=1024 H=16 dh=64 T=1152
// ============================================================================

typedef __attribute__((ext_vector_type(8))) short bf16x8;
typedef __attribute__((ext_vector_type(4))) float f32x4;

#define MFMA16(a, b, c) __builtin_amdgcn_mfma_f32_16x16x32_bf16((a), (b), (c), 0, 0, 0)

#define GLOAD_LDS16(g, l)                                                  \
    __builtin_amdgcn_global_load_lds(                                      \
        (const __attribute__((address_space(1))) void*)(const void*)(g),   \
        (__attribute__((address_space(3))) void*)(void*)(l), 16, 0, 0)

static __device__ __forceinline__ unsigned short f2bf(float f) {
    union { float f; unsigned int u; } v; v.f = f;
    unsigned int u = v.u;
    return (unsigned short)((u + 0x7fffu + ((u >> 16) & 1u)) >> 16);  // RNE
}

// ---------------------------------------------------------------------------
// Merged fp32->bf16 for x (4M elems) and M (0.5M elems); 4 elems/thread.
__global__ void cvt_all(const float* __restrict__ x, const float* __restrict__ Mem,
                        unsigned short* __restrict__ x_bf, unsigned short* __restrict__ M_bf) {
    int i = blockIdx.x * 256 + threadIdx.x;
    if (i < 1048576) {
        float4 v = ((const float4*)x)[i];
        ushort4 o; o.x = f2bf(v.x); o.y = f2bf(v.y); o.z = f2bf(v.z); o.w = f2bf(v.w);
        ((ushort4*)x_bf)[i] = o;
    } else {
        int j = i - 1048576;
        float4 v = ((const float4*)Mem)[j];
        ushort4 o; o.x = f2bf(v.x); o.y = f2bf(v.y); o.z = f2bf(v.z); o.w = f2bf(v.w);
        ((ushort4*)M_bf)[j] = o;
    }
}

// ---------------------------------------------------------------------------
static __device__ __forceinline__ void transpose_body(const float* __restrict__ W,
                                                      unsigned short* __restrict__ Wt,
                                                      int K, int N, int bx, int by,
                                                      float (*tile)[33]) {
    int n0 = bx * 32, k0 = by * 32;
    int tx = threadIdx.x & 31, ty = threadIdx.x >> 5;
    #pragma unroll
    for (int r = ty; r < 32; r += 8) tile[r][tx] = W[(size_t)(k0 + r) * N + n0 + tx];
    __syncthreads();
    #pragma unroll
    for (int r = ty; r < 32; r += 8) Wt[(size_t)(n0 + r) * K + k0 + tx] = f2bf(tile[tx][r]);
}

// Merged: 3 weight transpose-converts + key-bias build (pre-scaled by log2 e).
__global__ void prep_weights(const float* __restrict__ W_attn, const float* __restrict__ W_mem,
                             const float* __restrict__ W_proj, unsigned short* __restrict__ Wat,
                             unsigned short* __restrict__ Wmt, unsigned short* __restrict__ Wpt,
                             const float* __restrict__ Mmask, const float* __restrict__ amask,
                             float* __restrict__ biasT) {
    __shared__ float tile[32][33];
    int bid = blockIdx.x;
    if (bid < 3072) {
        transpose_body(W_attn, Wat, 1024, 3072, bid % 96, bid / 96, tile);
    } else if (bid < 5120) {
        int t = bid - 3072; transpose_body(W_mem, Wmt, 1024, 2048, t % 64, t / 64, tile);
    } else if (bid < 6144) {
        int t = bid - 5120; transpose_body(W_proj, Wpt, 1024, 1024, t % 32, t / 32, tile);
    } else {
        int i = (bid - 6144) * 256 + threadIdx.x;
        if (i < 4 * 1152) {
            int b = i / 1152, t = i % 1152;
            float v = (t < 128) ? (Mmask[b * 128 + t] - 1.f) * 10000.f
                                : amask[b * 1024 + t - 128];
            biasT[i] = v * 1.4426950408889634f;
        }
    }
}

// ---------------------------------------------------------------------------
// Rearrange K/V: Kc[b*h][t][64], Vt[b*h][64][t] from EKV (t<128) / QKV.
__global__ __launch_bounds__(256) void build_kv(const unsigned short* __restrict__ QKV,
                                                const unsigned short* __restrict__ EKV,
                                                unsigned short* __restrict__ Kc,
                                                unsigned short* __restrict__ Vt) {
    __shared__ unsigned short vt[64][72];
    const int tid = threadIdx.x;
    const int blk = blockIdx.x;            // B*H*18
    const int tc = blk % 18, bh = blk / 18;
    const int h = bh & 15, b = bh >> 4;
    const int row = tid >> 2, c = (tid & 3) * 16;
    const int tg = tc * 64 + row;
    const unsigned short* src;
    if (tg < 128) src = EKV + (size_t)(b * 128 + tg) * 2048 + h * 64 + c;
    else          src = QKV + (size_t)(b * 1024 + tg - 128) * 3072 + 1024 + h * 64 + c;
    bf16x8 ka = *(const bf16x8*)src;
    bf16x8 kb = *(const bf16x8*)(src + 8);
    bf16x8 va = *(const bf16x8*)(src + 1024);
    bf16x8 vb = *(const bf16x8*)(src + 1032);
    unsigned short* kd = Kc + (size_t)bh * 73728 + (size_t)tg * 64 + c;
    *(bf16x8*)kd = ka;
    *(bf16x8*)(kd + 8) = kb;
    *(bf16x8*)&vt[row][c] = va;
    *(bf16x8*)&vt[row][c + 8] = vb;
    __syncthreads();
    bf16x8 o0, o1;
    #pragma unroll
    for (int j = 0; j < 8; j++) { o0[j] = vt[c + j][row]; o1[j] = vt[c + 8 + j][row]; }
    unsigned short* vd = Vt + (size_t)bh * 73728 + (size_t)row * 1152 + tc * 64 + c;
    *(bf16x8*)vd = o0;
    *(bf16x8*)(vd + 8) = o1;
}

// ---------------------------------------------------------------------------
// GEMM body: C[128-tile][TN-tile] = A x Bt^T + bias. m97 staging
// (global_load_lds width 16, unpadded [rows][32] LDS), BK=32, 4 waves.
// TN=128: waves 64x64 (4x4 MFMA); TN=64: waves 64x32 (4x2 MFMA).
template <int TN, int STORE_BF16>
static __device__ __forceinline__ void gemm_body(const unsigned short* __restrict__ A,
                                                 const unsigned short* __restrict__ Bt,
                                                 const float* __restrict__ bias,
                                                 void* __restrict__ C, int bm, int bn,
                                                 int N, int K,
                                                 unsigned short* As, unsigned short* Bs) {
    constexpr int NJ = TN / 32;        // wave n-tiles
    constexpr int NCH = 8 + TN / 16;   // 1KB staging chunks total
    const int tid = threadIdx.x;
    const int lane = tid & 63, wave = tid >> 6;
    const int quad = lane >> 4, l16 = lane & 15;
    const int wm = (wave & 1) * 64, wn = (wave >> 1) * (TN / 2);
    const int crow = lane >> 2, ccol = (lane & 3) * 8;
    const unsigned short* Abase = A + (size_t)(bm * 128 + crow) * K + ccol;
    const unsigned short* Bbase = Bt + (size_t)(bn * TN + crow) * K + ccol;

    f32x4 acc[4][NJ] = {};
    for (int k0 = 0; k0 < K; k0 += 32) {
        __syncthreads();
        #pragma unroll
        for (int cc = 0; cc < NCH / 4; cc++) {
            const int c = wave * (NCH / 4) + cc;
            if (c < 8) GLOAD_LDS16(Abase + (size_t)(c * 16) * K + k0, &As[c * 512]);
            else       GLOAD_LDS16(Bbase + (size_t)((c - 8) * 16) * K + k0, &Bs[(c - 8) * 512]);
        }
        __syncthreads();
        bf16x8 af[4], bf[NJ];
        #pragma unroll
        for (int i = 0; i < 4; i++) af[i] = *(const bf16x8*)&As[(wm + i * 16 + l16) * 32 + quad * 8];
        #pragma unroll
        for (int j = 0; j < NJ; j++) bf[j] = *(const bf16x8*)&Bs[(wn + j * 16 + l16) * 32 + quad * 8];
        #pragma unroll
        for (int i = 0; i < 4; i++)
            #pragma unroll
            for (int j = 0; j < NJ; j++)
                acc[i][j] = MFMA16(af[i], bf[j], acc[i][j]);
    }
    float bj[NJ];
    #pragma unroll
    for (int j = 0; j < NJ; j++) bj[j] = bias[bn * TN + wn + j * 16 + l16];
    #pragma unroll
    for (int i = 0; i < 4; i++) {
        const int row = bm * 128 + wm + i * 16 + quad * 4;
        #pragma unroll
        for (int j = 0; j < NJ; j++) {
            const int col = bn * TN + wn + j * 16 + l16;
            #pragma unroll
            for (int r = 0; r < 4; r++) {
                float v = acc[i][j][r] + bj[j];
                if (STORE_BF16)
                    ((unsigned short*)C)[(size_t)(row + r) * N + col] = f2bf(v);
                else
                    ((float*)C)[(size_t)(row + r) * N + col] = v;
            }
        }
    }
}

// Fused QKV (768 blocks) + EKV (64 blocks) in one launch.
__global__ __launch_bounds__(256) void gemm_qkv_ekv(const unsigned short* __restrict__ x_bf,
                                                    const unsigned short* __restrict__ Wat,
                                                    const float* __restrict__ b_attn,
                                                    unsigned short* __restrict__ QKV,
                                                    const unsigned short* __restrict__ M_bf,
                                                    const unsigned short* __restrict__ Wmt,
                                                    const float* __restrict__ b_mem,
                                                    unsigned short* __restrict__ EKV) {
    __shared__ unsigned short As[128 * 32];
    __shared__ unsigned short Bs[128 * 32];
    const int bid = blockIdx.x;
    if (bid < 768)
        gemm_body<128, 1>(x_bf, Wat, b_attn, QKV, bid & 31, bid >> 5, 3072, 1024, As, Bs);
    else {
        const int t = bid - 768;
        gemm_body<128, 1>(M_bf, Wmt, b_mem, EKV, t & 3, t >> 2, 2048, 1024, As, Bs);
    }
}

// proj: 128x64 tiles, 512 blocks, fp32 out.
__global__ __launch_bounds__(256) void gemm_proj(const unsigned short* __restrict__ Abuf,
                                                 const unsigned short* __restrict__ Wpt,
                                                 const float* __restrict__ b_proj,
                                                 float* __restrict__ out) {
    __shared__ unsigned short As[128 * 32];
    __shared__ unsigned short Bs[64 * 32];
    const int bid = blockIdx.x;
    gemm_body<64, 0>(Abuf, Wpt, b_proj, out, bid & 31, bid >> 5, 1024, 1024, As, Bs);
}

// ---------------------------------------------------------------------------
// Attention v4: block = (b,h, 32 q-rows), 4 waves split the t-range
// (t0 = wave*64, stride 256) -- no barriers in the main loop. K/V fragments
// direct from global (Kc [t][64], Vt [64][t]); den via MFMA(P, ones).
// Epilogue: partials combined through LDS (stride-66 padding, 2-way max).
__global__ __launch_bounds__(256) void attn_kernel(const unsigned short* __restrict__ QKV,
                                                   const unsigned short* __restrict__ Kc,
                                                   const unsigned short* __restrict__ Vt,
                                                   const float* __restrict__ biasT,
                                                   unsigned short* __restrict__ Aout) {
    __shared__ char smem[34304];
    float* On = (float*)smem;                    // [4][32][66] (epilogue)
    float* Dn = (float*)(smem + 33792);          // [4][32]
    unsigned short* Ps = (unsigned short*)smem;  // [4][32*72] (main loop only)
    const int tid = threadIdx.x;
    const int lane = tid & 63, wave = tid >> 6;
    const int quad = lane >> 4, l16 = lane & 15;
    const int blk = blockIdx.x;                  // 2048 = 32 qg x 64 bh
    const int qg = 31 - (blk >> 6);              // longest blocks first
    const int bh = blk & 63;
    const int h = bh & 15, b = bh >> 4;
    const int qrow0 = qg * 32;

    bf16x8 qf[2][2];
    #pragma unroll
    for (int sm = 0; sm < 2; sm++)
        #pragma unroll
        for (int k2 = 0; k2 < 2; k2++)
            qf[sm][k2] = *(const bf16x8*)(QKV + (size_t)(b * 1024 + qrow0 + sm * 16 + l16) * 3072 +
                                          h * 64 + k2 * 32 + quad * 8);

    const unsigned short* Kb = Kc + (size_t)bh * 73728;
    const unsigned short* Vb = Vt + (size_t)bh * 73728;
    const float* bias_b = biasT + b * 1152;

    bf16x8 ones;
    #pragma unroll
    for (int j = 0; j < 8; j++) ones[j] = (short)0x3F80;  // bf16 1.0

    f32x4 o[2][4] = {};
    f32x4 oden[2] = {};
    const int tmax = min(1152, ((qrow0 + 223) >> 6) << 6);

    for (int t0 = wave * 64; t0 < tmax; t0 += 256) {
        bf16x8 kf[4][2], vf[2][4];
        #pragma unroll
        for (int tn = 0; tn < 4; tn++) {
            const unsigned short* kp = Kb + (size_t)(t0 + tn * 16 + l16) * 64 + quad * 8;
            kf[tn][0] = *(const bf16x8*)kp;
            kf[tn][1] = *(const bf16x8*)(kp + 32);
        }
        #pragma unroll
        for (int tk = 0; tk < 2; tk++)
            #pragma unroll
            for (int dn = 0; dn < 4; dn++)
                vf[tk][dn] = *(const bf16x8*)(Vb + (size_t)(dn * 16 + l16) * 1152 +
                                              t0 + tk * 32 + quad * 8);
        float4 bt[4];
        #pragma unroll
        for (int tn = 0; tn < 4; tn++)
            bt[tn] = *(const float4*)(bias_b + t0 + tn * 16 + quad * 4);

        const bool nomask = (t0 + 63 <= 128 + qrow0);
        #pragma unroll
        for (int sm = 0; sm < 2; sm++) {
            const int sg = qrow0 + sm * 16 + l16;
            #pragma unroll
            for (int tn = 0; tn < 4; tn++) {
                f32x4 st = {};
                st = MFMA16(kf[tn][0], qf[sm][0], st);
                st = MFMA16(kf[tn][1], qf[sm][1], st);
                float p[4];
                #pragma unroll
                for (int r = 0; r < 4; r++) {
                    float e = __builtin_amdgcn_exp2f(st[r] * 0.18033688011112042f + bt[tn][r]);
                    if (!nomask) {
                        const int tg = t0 + tn * 16 + quad * 4 + r;
                        e = (tg < 128 || tg - 128 <= sg) ? e : 0.f;
                    }
                    p[r] = e;
                }
                union { ushort4 u; __hip_bfloat162 h2[2]; } pk;
                pk.h2[0] = __float22bfloat162_rn(float2{p[0], p[1]});
                pk.h2[1] = __float22bfloat162_rn(float2{p[2], p[3]});
                *(ushort4*)&Ps[wave * 2304 + (sm * 16 + l16) * 72 + tn * 16 + quad * 4] = pk.u;
            }
        }
        #pragma unroll
        for (int sm = 0; sm < 2; sm++) {
            #pragma unroll
            for (int tk = 0; tk < 2; tk++) {
                bf16x8 pf = *(const bf16x8*)&Ps[wave * 2304 + (sm * 16 + l16) * 72 +
                                                tk * 32 + quad * 8];
                oden[sm] = MFMA16(pf, ones, oden[sm]);
                #pragma unroll
                for (int dn = 0; dn < 4; dn++)
                    o[sm][dn] = MFMA16(pf, vf[tk][dn], o[sm][dn]);
            }
        }
    }

    __syncthreads();  // all waves done with Ps; smem is now On/Dn
    #pragma unroll
    for (int sm = 0; sm < 2; sm++) {
        #pragma unroll
        for (int dn = 0; dn < 4; dn++)
            #pragma unroll
            for (int r = 0; r < 4; r++)
                On[wave * 2112 + (sm * 16 + quad * 4 + r) * 66 + dn * 16 + l16] = o[sm][dn][r];
        if (l16 == 0)
            #pragma unroll
            for (int r = 0; r < 4; r++)
                Dn[wave * 32 + sm * 16 + quad * 4 + r] = oden[sm][r];
    }
    __syncthreads();

    // combine: thread -> (row = tid>>3, 8 cols)
    const int row = tid >> 3, c0 = (tid & 7) * 8;
    float den = 0.f, a8[8] = {};
    #pragma unroll
    for (int w = 0; w < 4; w++) {
        den += Dn[w * 32 + row];
        #pragma unroll
        for (int j = 0; j < 8; j++) a8[j] += On[w * 2112 + row * 66 + c0 + j];
    }
    const float inv = 1.f / den;
    bf16x8 o8;
    #pragma unroll
    for (int j = 0; j < 8; j++) o8[j] = (short)f2bf(a8[j] * inv);
    *(bf16x8*)&Aout[(size_t)(b * 1024 + qrow0 + row) * 1024 + h * 64 + c0] = o8;
}

// ---------------------------------------------------------------------------
extern "C" void kernel_launch(void* const* d_in, const int* in_sizes, int n_in,
                              void* d_out, int out_size, void* d_ws, size_t ws_size,
                              hipStream_t stream) {
    const float* x      = (const float*)d_in[0];
    const float* Mem    = (const float*)d_in[1];
    const float* Mmask  = (const float*)d_in[2];
    const float* amask  = (const float*)d_in[3];
    const float* W_attn = (const float*)d_in[4];
    const float* b_attn = (const float*)d_in[5];
    const float* W_mem  = (const float*)d_in[6];
    const float* b_mem  = (const float*)d_in[7];
    const float* W_proj = (const float*)d_in[8];
    const float* b_proj = (const float*)d_in[9];
    float* out = (float*)d_out;

    char* ws = (char*)d_ws;
    unsigned short* x_bf  = (unsigned short*)ws;  ws += (size_t)4096 * 1024 * 2;
    unsigned short* M_bf  = (unsigned short*)ws;  ws += (size_t)512 * 1024 * 2;
    unsigned short* Wat   = (unsigned short*)ws;  ws += (size_t)3072 * 1024 * 2;
    unsigned short* Wmt   = (unsigned short*)ws;  ws += (size_t)2048 * 1024 * 2;
    unsigned short* Wpt   = (unsigned short*)ws;  ws += (size_t)1024 * 1024 * 2;
    unsigned short* QKV   = (unsigned short*)ws;  ws += (size_t)4096 * 3072 * 2;
    unsigned short* EKV   = (unsigned short*)ws;  ws += (size_t)512 * 2048 * 2;
    unsigned short* Abuf  = (unsigned short*)ws;  ws += (size_t)4096 * 1024 * 2;
    unsigned short* Kc    = (unsigned short*)ws;  ws += (size_t)64 * 1152 * 64 * 2;
    unsigned short* Vt    = (unsigned short*)ws;  ws += (size_t)64 * 64 * 1152 * 2;
    float*          biasT = (float*)ws;           ws += (size_t)4 * 1152 * 4;
    // total ws use: ~77 MB

    cvt_all<<<4608, 256, 0, stream>>>(x, Mem, x_bf, M_bf);
    prep_weights<<<6163, 256, 0, stream>>>(W_attn, W_mem, W_proj, Wat, Wmt, Wpt,
                                           Mmask, amask, biasT);
    gemm_qkv_ekv<<<832, 256, 0, stream>>>(x_bf, Wat, b_attn, QKV, M_bf, Wmt, b_mem, EKV);
    build_kv<<<1152, 256, 0, stream>>>(QKV, EKV, Kc, Vt);
    attn_kernel<<<2048, 256, 0, stream>>>(QKV, Kc, Vt, biasT, Abuf);
    gemm_proj<<<512, 256, 0, stream>>>(Abuf, Wpt, b_proj, out);
}

// Round 5
// 227.462 us; speedup vs baseline: 1.2829x; 1.0436x over previous
//
#include <hip/hip_runtime.h>
#include <hip/hip_bf16.h>

// ============================================================================
// ExtraAttention on MI355X (gfx950), bf16 MFMA pipeline.
// R5: attention rewritten for DATA REUSE — K/V staged to LDS once per block
//     (64 q-rows, 4 waves share), m97 global_load_lds staging, XCD-aware
//     swizzle so each bh's K/V slice stays in its home XCD L2.
// Dims: B=4 S=1024 P=128 NX=1024 H=16 dh=64 T=1152
// ============================================================================

typedef __attribute__((ext_vector_type(8))) short bf16x8;
typedef __attribute__((ext_vector_type(4))) float f32x4;

#define MFMA16(a, b, c) __builtin_amdgcn_mfma_f32_16x16x32_bf16((a), (b), (c), 0, 0, 0)

#define GLOAD_LDS16(g, l)                                                  \
    __builtin_amdgcn_global_load_lds(                                      \
        (const __attribute__((address_space(1))) void*)(const void*)(g),   \
        (__attribute__((address_space(3))) void*)(void*)(l), 16, 0, 0)

static __device__ __forceinline__ unsigned short f2bf(float f) {
    union { float f; unsigned int u; } v; v.f = f;
    unsigned int u = v.u;
    return (unsigned short)((u + 0x7fffu + ((u >> 16) & 1u)) >> 16);  // RNE
}

// ---------------------------------------------------------------------------
__global__ void cvt_all(const float* __restrict__ x, const float* __restrict__ Mem,
                        unsigned short* __restrict__ x_bf, unsigned short* __restrict__ M_bf) {
    int i = blockIdx.x * 256 + threadIdx.x;
    if (i < 1048576) {
        float4 v = ((const float4*)x)[i];
        ushort4 o; o.x = f2bf(v.x); o.y = f2bf(v.y); o.z = f2bf(v.z); o.w = f2bf(v.w);
        ((ushort4*)x_bf)[i] = o;
    } else {
        int j = i - 1048576;
        float4 v = ((const float4*)Mem)[j];
        ushort4 o; o.x = f2bf(v.x); o.y = f2bf(v.y); o.z = f2bf(v.z); o.w = f2bf(v.w);
        ((ushort4*)M_bf)[j] = o;
    }
}

// ---------------------------------------------------------------------------
static __device__ __forceinline__ void transpose_body(const float* __restrict__ W,
                                                      unsigned short* __restrict__ Wt,
                                                      int K, int N, int bx, int by,
                                                      float (*tile)[33]) {
    int n0 = bx * 32, k0 = by * 32;
    int tx = threadIdx.x & 31, ty = threadIdx.x >> 5;
    #pragma unroll
    for (int r = ty; r < 32; r += 8) tile[r][tx] = W[(size_t)(k0 + r) * N + n0 + tx];
    __syncthreads();
    #pragma unroll
    for (int r = ty; r < 32; r += 8) Wt[(size_t)(n0 + r) * K + k0 + tx] = f2bf(tile[tx][r]);
}

__global__ void prep_weights(const float* __restrict__ W_attn, const float* __restrict__ W_mem,
                             const float* __restrict__ W_proj, unsigned short* __restrict__ Wat,
                             unsigned short* __restrict__ Wmt, unsigned short* __restrict__ Wpt,
                             const float* __restrict__ Mmask, const float* __restrict__ amask,
                             float* __restrict__ biasT) {
    __shared__ float tile[32][33];
    int bid = blockIdx.x;
    if (bid < 3072) {
        transpose_body(W_attn, Wat, 1024, 3072, bid % 96, bid / 96, tile);
    } else if (bid < 5120) {
        int t = bid - 3072; transpose_body(W_mem, Wmt, 1024, 2048, t % 64, t / 64, tile);
    } else if (bid < 6144) {
        int t = bid - 5120; transpose_body(W_proj, Wpt, 1024, 1024, t % 32, t / 32, tile);
    } else {
        int i = (bid - 6144) * 256 + threadIdx.x;
        if (i < 4 * 1152) {
            int b = i / 1152, t = i % 1152;
            float v = (t < 128) ? (Mmask[b * 128 + t] - 1.f) * 10000.f
                                : amask[b * 1024 + t - 128];
            biasT[i] = v * 1.4426950408889634f;
        }
    }
}

// ---------------------------------------------------------------------------
// Rearrange K/V: Kc[b*h][t][64], Vt[b*h][64][t] from EKV (t<128) / QKV.
__global__ __launch_bounds__(256) void build_kv(const unsigned short* __restrict__ QKV,
                                                const unsigned short* __restrict__ EKV,
                                                unsigned short* __restrict__ Kc,
                                                unsigned short* __restrict__ Vt) {
    __shared__ unsigned short vt[64][72];
    const int tid = threadIdx.x;
    const int blk = blockIdx.x;            // B*H*18
    const int tc = blk % 18, bh = blk / 18;
    const int h = bh & 15, b = bh >> 4;
    const int row = tid >> 2, c = (tid & 3) * 16;
    const int tg = tc * 64 + row;
    const unsigned short* src;
    if (tg < 128) src = EKV + (size_t)(b * 128 + tg) * 2048 + h * 64 + c;
    else          src = QKV + (size_t)(b * 1024 + tg - 128) * 3072 + 1024 + h * 64 + c;
    bf16x8 ka = *(const bf16x8*)src;
    bf16x8 kb = *(const bf16x8*)(src + 8);
    bf16x8 va = *(const bf16x8*)(src + 1024);
    bf16x8 vb = *(const bf16x8*)(src + 1032);
    unsigned short* kd = Kc + (size_t)bh * 73728 + (size_t)tg * 64 + c;
    *(bf16x8*)kd = ka;
    *(bf16x8*)(kd + 8) = kb;
    *(bf16x8*)&vt[row][c] = va;
    *(bf16x8*)&vt[row][c + 8] = vb;
    __syncthreads();
    bf16x8 o0, o1;
    #pragma unroll
    for (int j = 0; j < 8; j++) { o0[j] = vt[c + j][row]; o1[j] = vt[c + 8 + j][row]; }
    unsigned short* vd = Vt + (size_t)bh * 73728 + (size_t)row * 1152 + tc * 64 + c;
    *(bf16x8*)vd = o0;
    *(bf16x8*)(vd + 8) = o1;
}

// ---------------------------------------------------------------------------
// GEMM body (m97 staging). TN=128: waves 64x64; TN=64: waves 64x32.
template <int TN, int STORE_BF16>
static __device__ __forceinline__ void gemm_body(const unsigned short* __restrict__ A,
                                                 const unsigned short* __restrict__ Bt,
                                                 const float* __restrict__ bias,
                                                 void* __restrict__ C, int bm, int bn,
                                                 int N, int K,
                                                 unsigned short* As, unsigned short* Bs) {
    constexpr int NJ = TN / 32;
    constexpr int NCH = 8 + TN / 16;
    const int tid = threadIdx.x;
    const int lane = tid & 63, wave = tid >> 6;
    const int quad = lane >> 4, l16 = lane & 15;
    const int wm = (wave & 1) * 64, wn = (wave >> 1) * (TN / 2);
    const int crow = lane >> 2, ccol = (lane & 3) * 8;
    const unsigned short* Abase = A + (size_t)(bm * 128 + crow) * K + ccol;
    const unsigned short* Bbase = Bt + (size_t)(bn * TN + crow) * K + ccol;

    f32x4 acc[4][NJ] = {};
    for (int k0 = 0; k0 < K; k0 += 32) {
        __syncthreads();
        #pragma unroll
        for (int cc = 0; cc < NCH / 4; cc++) {
            const int c = wave * (NCH / 4) + cc;
            if (c < 8) GLOAD_LDS16(Abase + (size_t)(c * 16) * K + k0, &As[c * 512]);
            else       GLOAD_LDS16(Bbase + (size_t)((c - 8) * 16) * K + k0, &Bs[(c - 8) * 512]);
        }
        __syncthreads();
        bf16x8 af[4], bf[NJ];
        #pragma unroll
        for (int i = 0; i < 4; i++) af[i] = *(const bf16x8*)&As[(wm + i * 16 + l16) * 32 + quad * 8];
        #pragma unroll
        for (int j = 0; j < NJ; j++) bf[j] = *(const bf16x8*)&Bs[(wn + j * 16 + l16) * 32 + quad * 8];
        #pragma unroll
        for (int i = 0; i < 4; i++)
            #pragma unroll
            for (int j = 0; j < NJ; j++)
                acc[i][j] = MFMA16(af[i], bf[j], acc[i][j]);
    }
    float bj[NJ];
    #pragma unroll
    for (int j = 0; j < NJ; j++) bj[j] = bias[bn * TN + wn + j * 16 + l16];
    #pragma unroll
    for (int i = 0; i < 4; i++) {
        const int row = bm * 128 + wm + i * 16 + quad * 4;
        #pragma unroll
        for (int j = 0; j < NJ; j++) {
            const int col = bn * TN + wn + j * 16 + l16;
            #pragma unroll
            for (int r = 0; r < 4; r++) {
                float v = acc[i][j][r] + bj[j];
                if (STORE_BF16)
                    ((unsigned short*)C)[(size_t)(row + r) * N + col] = f2bf(v);
                else
                    ((float*)C)[(size_t)(row + r) * N + col] = v;
            }
        }
    }
}

__global__ __launch_bounds__(256) void gemm_qkv_ekv(const unsigned short* __restrict__ x_bf,
                                                    const unsigned short* __restrict__ Wat,
                                                    const float* __restrict__ b_attn,
                                                    unsigned short* __restrict__ QKV,
                                                    const unsigned short* __restrict__ M_bf,
                                                    const unsigned short* __restrict__ Wmt,
                                                    const float* __restrict__ b_mem,
                                                    unsigned short* __restrict__ EKV) {
    __shared__ unsigned short As[128 * 32];
    __shared__ unsigned short Bs[128 * 32];
    const int bid = blockIdx.x;
    if (bid < 768)
        gemm_body<128, 1>(x_bf, Wat, b_attn, QKV, bid & 31, bid >> 5, 3072, 1024, As, Bs);
    else {
        const int t = bid - 768;
        gemm_body<128, 1>(M_bf, Wmt, b_mem, EKV, t & 3, t >> 2, 2048, 1024, As, Bs);
    }
}

__global__ __launch_bounds__(256) void gemm_proj(const unsigned short* __restrict__ Abuf,
                                                 const unsigned short* __restrict__ Wpt,
                                                 const float* __restrict__ b_proj,
                                                 float* __restrict__ out) {
    __shared__ unsigned short As[128 * 32];
    __shared__ unsigned short Bs[64 * 32];
    const int bid = blockIdx.x;
    gemm_body<64, 0>(Abuf, Wpt, b_proj, out, bid & 31, bid >> 5, 1024, 1024, As, Bs);
}

// ---------------------------------------------------------------------------
// Attention v5: block = (b,h, 64 q-rows), 4 waves x 16 q-rows. K/V 64-t tile
// staged ONCE per block into LDS via global_load_lds (m97 2-barrier), shared
// by all 4 waves (4x traffic reduction vs v4). XCD swizzle: blk&7 = xcd, each
// xcd owns 8 bh (2.35MB K/V < 4MiB L2). den via MFMA(P, ones).
// LDS layouts: Ks[k2][64][32], Vs[tk][64][32] (m97 read pattern), Ps/wave
// [16s][72t]. Per-wave causal skip keeps barrier participation.
__global__ __launch_bounds__(256) void attn_kernel(const unsigned short* __restrict__ QKV,
                                                   const unsigned short* __restrict__ Kc,
                                                   const unsigned short* __restrict__ Vt,
                                                   const float* __restrict__ biasT,
                                                   unsigned short* __restrict__ Aout) {
    __shared__ unsigned short Ks[2 * 64 * 32];
    __shared__ unsigned short Vs[2 * 64 * 32];
    __shared__ unsigned short Ps[4][16 * 72];
    const int tid = threadIdx.x;
    const int lane = tid & 63, wave = tid >> 6;
    const int quad = lane >> 4, l16 = lane & 15;
    const int blk = blockIdx.x;                 // 1024
    const int xcd = blk & 7, idx = blk >> 3;    // XCD-home swizzle
    const int bh = xcd * 8 + (idx >> 4);        // 8 bh per XCD
    const int qg = 15 - (idx & 15);             // longest first within bh
    const int h = bh & 15, b = bh >> 4;
    const int qrow0 = qg * 64;
    const int qrow_w = qrow0 + wave * 16;

    bf16x8 qf[2];
    #pragma unroll
    for (int k2 = 0; k2 < 2; k2++)
        qf[k2] = *(const bf16x8*)(QKV + (size_t)(b * 1024 + qrow_w + l16) * 3072 +
                                  h * 64 + k2 * 32 + quad * 8);

    const unsigned short* Kb = Kc + (size_t)bh * 73728;
    const unsigned short* Vb = Vt + (size_t)bh * 73728;
    const float* bias_b = biasT + b * 1152;

    const int srow = lane >> 2;        // staging: 16 rows x 64B per 1KB chunk
    const int sc8 = (lane & 3) * 8;

    bf16x8 ones;
    #pragma unroll
    for (int j = 0; j < 8; j++) ones[j] = (short)0x3F80;  // bf16 1.0

    f32x4 o[4] = {};
    f32x4 oden = {};
    const int tmax = min(1152, qrow0 + 192);

    for (int t0 = 0; t0 < tmax; t0 += 64) {
        __syncthreads();  // all waves done reading previous tile
        #pragma unroll
        for (int cc = 0; cc < 4; cc++) {
            const int c = wave * 4 + cc;
            if (c < 8) {  // K: chunk -> [k2 = c&1][rows (c>>1)*16 + srow]
                const int kk = c & 1, rch = c >> 1;
                GLOAD_LDS16(Kb + (size_t)(t0 + rch * 16 + srow) * 64 + kk * 32 + sc8,
                            &Ks[kk * 2048 + rch * 512]);
            } else {      // V: chunk -> [tk = c2&1][rows (c2>>1)*16 + srow]
                const int c2 = c - 8, tk = c2 & 1, dch = c2 >> 1;
                GLOAD_LDS16(Vb + (size_t)(dch * 16 + srow) * 1152 + t0 + tk * 32 + sc8,
                            &Vs[tk * 2048 + dch * 512]);
            }
        }
        __syncthreads();  // drains vmcnt -> staged tile visible
        if (t0 <= qrow_w + 143) {  // wave has >=1 causally-visible key in tile
            const bool nomask = (t0 + 63 <= 128 + qrow_w);
            float4 bt[4];
            #pragma unroll
            for (int tn = 0; tn < 4; tn++)
                bt[tn] = *(const float4*)(bias_b + t0 + tn * 16 + quad * 4);
            const int sg = qrow_w + l16;
            #pragma unroll
            for (int tn = 0; tn < 4; tn++) {
                bf16x8 kf0 = *(const bf16x8*)&Ks[0 * 2048 + (tn * 16 + l16) * 32 + quad * 8];
                bf16x8 kf1 = *(const bf16x8*)&Ks[1 * 2048 + (tn * 16 + l16) * 32 + quad * 8];
                f32x4 st = {};
                st = MFMA16(kf0, qf[0], st);
                st = MFMA16(kf1, qf[1], st);
                float p[4];
                #pragma unroll
                for (int r = 0; r < 4; r++) {
                    float e = __builtin_amdgcn_exp2f(st[r] * 0.18033688011112042f + bt[tn][r]);
                    if (!nomask) {
                        const int tg = t0 + tn * 16 + quad * 4 + r;
                        e = (tg < 128 || tg - 128 <= sg) ? e : 0.f;
                    }
                    p[r] = e;
                }
                union { ushort4 u; __hip_bfloat162 h2[2]; } pk;
                pk.h2[0] = __float22bfloat162_rn(float2{p[0], p[1]});
                pk.h2[1] = __float22bfloat162_rn(float2{p[2], p[3]});
                *(ushort4*)&Ps[wave][l16 * 72 + tn * 16 + quad * 4] = pk.u;
            }
            #pragma unroll
            for (int tk = 0; tk < 2; tk++) {
                bf16x8 pf = *(const bf16x8*)&Ps[wave][l16 * 72 + tk * 32 + quad * 8];
                oden = MFMA16(pf, ones, oden);
                #pragma unroll
                for (int dn = 0; dn < 4; dn++) {
                    bf16x8 vf = *(const bf16x8*)&Vs[tk * 2048 + (dn * 16 + l16) * 32 + quad * 8];
                    o[dn] = MFMA16(pf, vf, o[dn]);
                }
            }
        }
    }

    // epilogue: o C-layout row s = quad*4+r, col d = dn*16+l16; oden same rows
    #pragma unroll
    for (int r = 0; r < 4; r++) {
        const float inv = 1.f / oden[r];
        const size_t orow = (size_t)(b * 1024 + qrow_w + quad * 4 + r) * 1024 + h * 64;
        #pragma unroll
        for (int dn = 0; dn < 4; dn++)
            Aout[orow + dn * 16 + l16] = f2bf(o[dn][r] * inv);
    }
}

// ---------------------------------------------------------------------------
extern "C" void kernel_launch(void* const* d_in, const int* in_sizes, int n_in,
                              void* d_out, int out_size, void* d_ws, size_t ws_size,
                              hipStream_t stream) {
    const float* x      = (const float*)d_in[0];
    const float* Mem    = (const float*)d_in[1];
    const float* Mmask  = (const float*)d_in[2];
    const float* amask  = (const float*)d_in[3];
    const float* W_attn = (const float*)d_in[4];
    const float* b_attn = (const float*)d_in[5];
    const float* W_mem  = (const float*)d_in[6];
    const float* b_mem  = (const float*)d_in[7];
    const float* W_proj = (const float*)d_in[8];
    const float* b_proj = (const float*)d_in[9];
    float* out = (float*)d_out;

    char* ws = (char*)d_ws;
    unsigned short* x_bf  = (unsigned short*)ws;  ws += (size_t)4096 * 1024 * 2;
    unsigned short* M_bf  = (unsigned short*)ws;  ws += (size_t)512 * 1024 * 2;
    unsigned short* Wat   = (unsigned short*)ws;  ws += (size_t)3072 * 1024 * 2;
    unsigned short* Wmt   = (unsigned short*)ws;  ws += (size_t)2048 * 1024 * 2;
    unsigned short* Wpt   = (unsigned short*)ws;  ws += (size_t)1024 * 1024 * 2;
    unsigned short* QKV   = (unsigned short*)ws;  ws += (size_t)4096 * 3072 * 2;
    unsigned short* EKV   = (unsigned short*)ws;  ws += (size_t)512 * 2048 * 2;
    unsigned short* Abuf  = (unsigned short*)ws;  ws += (size_t)4096 * 1024 * 2;
    unsigned short* Kc    = (unsigned short*)ws;  ws += (size_t)64 * 1152 * 64 * 2;
    unsigned short* Vt    = (unsigned short*)ws;  ws += (size_t)64 * 64 * 1152 * 2;
    float*          biasT = (float*)ws;           ws += (size_t)4 * 1152 * 4;
    // total ws use: ~77 MB

    cvt_all<<<4608, 256, 0, stream>>>(x, Mem, x_bf, M_bf);
    prep_weights<<<6163, 256, 0, stream>>>(W_attn, W_mem, W_proj, Wat, Wmt, Wpt,
                                           Mmask, amask, biasT);
    gemm_qkv_ekv<<<832, 256, 0, stream>>>(x_bf, Wat, b_attn, QKV, M_bf, Wmt, b_mem, EKV);
    build_kv<<<1152, 256, 0, stream>>>(QKV, EKV, Kc, Vt);
    attn_kernel<<<1024, 256, 0, stream>>>(QKV, Kc, Vt, biasT, Abuf);
    gemm_proj<<<512, 256, 0, stream>>>(Abuf, Wpt, b_proj, out);
}

// Round 6
// 209.409 us; speedup vs baseline: 1.3935x; 1.0862x over previous
//
#include <hip/hip_runtime.h>
#include <hip/hip_bf16.h>

// ============================================================================
// ExtraAttention on MI355X (gfx950), bf16 MFMA pipeline.
// R6: gemm grid fixed to exactly 4 blocks/CU (768 QKV 128x128 + 256 EKV 64x64
//     = 1024 blocks); build_kv folded into GEMM epilogue (q->Qbuf, k->Kc,
//     v->Vt via per-wave LDS transpose); cvt+prep fused. 4 kernels total.
// Dims: B=4 S=1024 P=128 NX=1024 H=16 dh=64 T=1152
// ============================================================================

typedef __attribute__((ext_vector_type(8))) short bf16x8;
typedef __attribute__((ext_vector_type(4))) float f32x4;

#define MFMA16(a, b, c) __builtin_amdgcn_mfma_f32_16x16x32_bf16((a), (b), (c), 0, 0, 0)

#define GLOAD_LDS16(g, l)                                                  \
    __builtin_amdgcn_global_load_lds(                                      \
        (const __attribute__((address_space(1))) void*)(const void*)(g),   \
        (__attribute__((address_space(3))) void*)(void*)(l), 16, 0, 0)

static __device__ __forceinline__ unsigned short f2bf(float f) {
    union { float f; unsigned int u; } v; v.f = f;
    unsigned int u = v.u;
    return (unsigned short)((u + 0x7fffu + ((u >> 16) & 1u)) >> 16);  // RNE
}

// ---------------------------------------------------------------------------
// Fused: fp32->bf16 converts (x, M) + 3 weight transposes + key-bias build.
static __device__ __forceinline__ void transpose_body(const float* __restrict__ W,
                                                      unsigned short* __restrict__ Wt,
                                                      int K, int N, int bx, int by,
                                                      float (*tile)[33]) {
    int n0 = bx * 32, k0 = by * 32;
    int tx = threadIdx.x & 31, ty = threadIdx.x >> 5;
    #pragma unroll
    for (int r = ty; r < 32; r += 8) tile[r][tx] = W[(size_t)(k0 + r) * N + n0 + tx];
    __syncthreads();
    #pragma unroll
    for (int r = ty; r < 32; r += 8) Wt[(size_t)(n0 + r) * K + k0 + tx] = f2bf(tile[tx][r]);
}

__global__ void prep_all(const float* __restrict__ x, const float* __restrict__ Mem,
                         unsigned short* __restrict__ x_bf, unsigned short* __restrict__ M_bf,
                         const float* __restrict__ W_attn, const float* __restrict__ W_mem,
                         const float* __restrict__ W_proj, unsigned short* __restrict__ Wat,
                         unsigned short* __restrict__ Wmt, unsigned short* __restrict__ Wpt,
                         const float* __restrict__ Mmask, const float* __restrict__ amask,
                         float* __restrict__ biasT) {
    __shared__ float tile[32][33];
    int bid = blockIdx.x;
    if (bid < 4608) {  // converts: 4608*256 threads, 4 elems each
        int i = bid * 256 + threadIdx.x;
        if (i < 1048576) {
            float4 v = ((const float4*)x)[i];
            ushort4 o; o.x = f2bf(v.x); o.y = f2bf(v.y); o.z = f2bf(v.z); o.w = f2bf(v.w);
            ((ushort4*)x_bf)[i] = o;
        } else {
            int j = i - 1048576;
            float4 v = ((const float4*)Mem)[j];
            ushort4 o; o.x = f2bf(v.x); o.y = f2bf(v.y); o.z = f2bf(v.z); o.w = f2bf(v.w);
            ((ushort4*)M_bf)[j] = o;
        }
        return;
    }
    bid -= 4608;
    if (bid < 3072) {
        transpose_body(W_attn, Wat, 1024, 3072, bid % 96, bid / 96, tile);
    } else if (bid < 5120) {
        int t = bid - 3072; transpose_body(W_mem, Wmt, 1024, 2048, t % 64, t / 64, tile);
    } else if (bid < 6144) {
        int t = bid - 5120; transpose_body(W_proj, Wpt, 1024, 1024, t % 32, t / 32, tile);
    } else {
        int i = (bid - 6144) * 256 + threadIdx.x;
        if (i < 4 * 1152) {
            int b = i / 1152, t = i % 1152;
            float v = (t < 128) ? (Mmask[b * 128 + t] - 1.f) * 10000.f
                                : amask[b * 1024 + t - 128];
            biasT[i] = v * 1.4426950408889634f;
        }
    }
}

// ---------------------------------------------------------------------------
// Fused QKV + EKV GEMM, 1024 blocks (exactly 4/CU), m97 staging (BK=32,
// global_load_lds width 16). Epilogue scatters to Qbuf / Kc[t][64] /
// Vt[64][t] (v via per-wave LDS transpose) -- build_kv eliminated.
__global__ __launch_bounds__(256, 4) void gemm_fused(
        const unsigned short* __restrict__ x_bf, const unsigned short* __restrict__ Wat,
        const float* __restrict__ b_attn, const unsigned short* __restrict__ M_bf,
        const unsigned short* __restrict__ Wmt, const float* __restrict__ b_mem,
        unsigned short* __restrict__ Qbuf, unsigned short* __restrict__ Kc,
        unsigned short* __restrict__ Vt) {
    __shared__ char smem[34816];
    unsigned short* As = (unsigned short*)smem;             // 8 KB staging
    unsigned short* Bs = (unsigned short*)(smem + 8192);    // 8 KB staging
    const int tid = threadIdx.x;
    const int lane = tid & 63, wave = tid >> 6;
    const int quad = lane >> 4, l16 = lane & 15;
    const int crow = lane >> 2, ccol = (lane & 3) * 8;      // staging lane map
    const int bid = blockIdx.x;

    if (bid < 768) {
        // ---------------- QKV: 128x128 tile, A=x_bf[4096][1024], Bt=Wat[3072][1024]
        const int bm = bid & 31, bn = bid >> 5;             // bn 0..23
        const int wm = (wave & 1) * 64, wn = (wave >> 1) * 64;
        const unsigned short* Abase = x_bf + (size_t)(bm * 128 + crow) * 1024 + ccol;
        const unsigned short* Bbase = Wat + (size_t)(bn * 128 + crow) * 1024 + ccol;
        f32x4 acc[4][4] = {};
        for (int k0 = 0; k0 < 1024; k0 += 32) {
            __syncthreads();
            #pragma unroll
            for (int cc = 0; cc < 4; cc++) {
                const int c = wave * 4 + cc;
                if (c < 8) GLOAD_LDS16(Abase + (size_t)(c * 16) * 1024 + k0, &As[c * 512]);
                else       GLOAD_LDS16(Bbase + (size_t)((c - 8) * 16) * 1024 + k0, &Bs[(c - 8) * 512]);
            }
            __syncthreads();
            bf16x8 af[4], bf[4];
            #pragma unroll
            for (int i = 0; i < 4; i++) af[i] = *(const bf16x8*)&As[(wm + i * 16 + l16) * 32 + quad * 8];
            #pragma unroll
            for (int j = 0; j < 4; j++) bf[j] = *(const bf16x8*)&Bs[(wn + j * 16 + l16) * 32 + quad * 8];
            #pragma unroll
            for (int i = 0; i < 4; i++)
                #pragma unroll
                for (int j = 0; j < 4; j++)
                    acc[i][j] = MFMA16(af[i], bf[j], acc[i][j]);
        }
        float bj[4];
        #pragma unroll
        for (int j = 0; j < 4; j++) bj[j] = b_attn[bn * 128 + wn + j * 16 + l16];
        __syncthreads();  // smem reuse: all waves done with As/Bs
        if (bn < 8) {
            // ---- q -> Qbuf[4096][1024]
            #pragma unroll
            for (int i = 0; i < 4; i++) {
                const int row = bm * 128 + wm + i * 16 + quad * 4;
                #pragma unroll
                for (int j = 0; j < 4; j++) {
                    const int col = bn * 128 + wn + j * 16 + l16;
                    #pragma unroll
                    for (int r = 0; r < 4; r++)
                        Qbuf[(size_t)(row + r) * 1024 + col] = f2bf(acc[i][j][r] + bj[j]);
                }
            }
        } else if (bn < 16) {
            // ---- k -> Kc[bh][t=s+128][d]
            #pragma unroll
            for (int i = 0; i < 4; i++) {
                const int row = bm * 128 + wm + i * 16 + quad * 4;
                const int b = row >> 10, s = row & 1023;
                #pragma unroll
                for (int j = 0; j < 4; j++) {
                    const int c = bn * 128 + wn + j * 16 + l16 - 1024;
                    unsigned short* kd = Kc + (size_t)((b << 4) | (c >> 6)) * 73728 +
                                         (size_t)(s + 128) * 64 + (c & 63);
                    #pragma unroll
                    for (int r = 0; r < 4; r++) kd[(size_t)r * 64] = f2bf(acc[i][j][r] + bj[j]);
                }
            }
        } else {
            // ---- v -> Vt[bh][d][t] via per-wave LDS transpose (64x64, stride 68)
            unsigned short* Tw = (unsigned short*)smem + wave * 4352;
            #pragma unroll
            for (int i = 0; i < 4; i++)
                #pragma unroll
                for (int j = 0; j < 4; j++)
                    #pragma unroll
                    for (int r = 0; r < 4; r++)
                        Tw[(j * 16 + l16) * 68 + i * 16 + quad * 4 + r] = f2bf(acc[i][j][r] + bj[j]);
            const int vb = (bn - 16) * 128 + wn;            // multiple of 64
            const int h = vb >> 6;
            const int b = bm >> 3, s0 = (bm * 128 + wm) & 1023;
            unsigned short* vd = Vt + (size_t)((b << 4) | h) * 73728 +
                                 (size_t)lane * 1152 + 128 + s0;
            #pragma unroll
            for (int ch = 0; ch < 8; ch++)
                *(bf16x8*)(vd + ch * 8) = *(const bf16x8*)&Tw[lane * 68 + ch * 8];
        }
    } else {
        // ---------------- EKV: 64x64 tile, A=M_bf[512][1024], Bt=Wmt[2048][1024]
        const int t = bid - 768;
        const int bm = t >> 5, bn = t & 31;                 // bm 0..7, bn 0..31
        const int wm = (wave & 1) * 32, wn = (wave >> 1) * 32;
        const unsigned short* Abase = M_bf + (size_t)(bm * 64 + crow) * 1024 + ccol;
        const unsigned short* Bbase = Wmt + (size_t)(bn * 64 + crow) * 1024 + ccol;
        f32x4 acc[2][2] = {};
        for (int k0 = 0; k0 < 1024; k0 += 32) {
            __syncthreads();
            #pragma unroll
            for (int cc = 0; cc < 2; cc++) {
                const int c = wave * 2 + cc;
                if (c < 4) GLOAD_LDS16(Abase + (size_t)(c * 16) * 1024 + k0, &As[c * 512]);
                else       GLOAD_LDS16(Bbase + (size_t)((c - 4) * 16) * 1024 + k0, &Bs[(c - 4) * 512]);
            }
            __syncthreads();
            bf16x8 af[2], bf[2];
            #pragma unroll
            for (int i = 0; i < 2; i++) af[i] = *(const bf16x8*)&As[(wm + i * 16 + l16) * 32 + quad * 8];
            #pragma unroll
            for (int j = 0; j < 2; j++) bf[j] = *(const bf16x8*)&Bs[(wn + j * 16 + l16) * 32 + quad * 8];
            #pragma unroll
            for (int i = 0; i < 2; i++)
                #pragma unroll
                for (int j = 0; j < 2; j++)
                    acc[i][j] = MFMA16(af[i], bf[j], acc[i][j]);
        }
        float bj[2];
        #pragma unroll
        for (int j = 0; j < 2; j++) bj[j] = b_mem[bn * 64 + wn + j * 16 + l16];
        __syncthreads();
        if (bn < 16) {
            // ---- ek -> Kc[bh][t=p][d], p<128
            #pragma unroll
            for (int i = 0; i < 2; i++) {
                const int row = bm * 64 + wm + i * 16 + quad * 4;
                const int b = row >> 7, p = row & 127;
                #pragma unroll
                for (int j = 0; j < 2; j++) {
                    const int c = bn * 64 + wn + j * 16 + l16;
                    unsigned short* kd = Kc + (size_t)((b << 4) | (c >> 6)) * 73728 +
                                         (size_t)p * 64 + (c & 63);
                    #pragma unroll
                    for (int r = 0; r < 4; r++) kd[(size_t)r * 64] = f2bf(acc[i][j][r] + bj[j]);
                }
            }
        } else {
            // ---- ev -> Vt[bh][d][p] via per-wave LDS transpose (32x32, stride 36)
            unsigned short* Tw = (unsigned short*)smem + wave * 1152;
            #pragma unroll
            for (int i = 0; i < 2; i++)
                #pragma unroll
                for (int j = 0; j < 2; j++)
                    #pragma unroll
                    for (int r = 0; r < 4; r++)
                        Tw[(j * 16 + l16) * 36 + i * 16 + quad * 4 + r] = f2bf(acc[i][j][r] + bj[j]);
            const int vb = bn * 64 + wn - 1024;             // multiple of 32
            const int h = vb >> 6, d0 = vb & 63;            // d0 in {0,32}
            const int b = (bm * 64 + wm) >> 7, p0 = (bm * 64 + wm) & 127;
            const int lc = lane >> 1, half = lane & 1;
            unsigned short* vd = Vt + (size_t)((b << 4) | h) * 73728 +
                                 (size_t)(d0 + lc) * 1152 + p0 + half * 16;
            #pragma unroll
            for (int ch = 0; ch < 2; ch++)
                *(bf16x8*)(vd + ch * 8) = *(const bf16x8*)&Tw[lc * 36 + half * 16 + ch * 8];
        }
    }
}

// ---------------------------------------------------------------------------
// Attention (R5 structure): block = (b,h, 64 q-rows), 4 waves x 16 q-rows,
// K/V staged once per block via global_load_lds, XCD-home swizzle,
// den via MFMA(P, ones). Q read from dense Qbuf.
__global__ __launch_bounds__(256) void attn_kernel(const unsigned short* __restrict__ Qbuf,
                                                   const unsigned short* __restrict__ Kc,
                                                   const unsigned short* __restrict__ Vt,
                                                   const float* __restrict__ biasT,
                                                   unsigned short* __restrict__ Aout) {
    __shared__ unsigned short Ks[2 * 64 * 32];
    __shared__ unsigned short Vs[2 * 64 * 32];
    __shared__ unsigned short Ps[4][16 * 72];
    const int tid = threadIdx.x;
    const int lane = tid & 63, wave = tid >> 6;
    const int quad = lane >> 4, l16 = lane & 15;
    const int blk = blockIdx.x;                 // 1024
    const int xcd = blk & 7, idx = blk >> 3;
    const int bh = xcd * 8 + (idx >> 4);
    const int qg = 15 - (idx & 15);
    const int h = bh & 15, b = bh >> 4;
    const int qrow0 = qg * 64;
    const int qrow_w = qrow0 + wave * 16;

    bf16x8 qf[2];
    #pragma unroll
    for (int k2 = 0; k2 < 2; k2++)
        qf[k2] = *(const bf16x8*)(Qbuf + (size_t)(b * 1024 + qrow_w + l16) * 1024 +
                                  h * 64 + k2 * 32 + quad * 8);

    const unsigned short* Kb = Kc + (size_t)bh * 73728;
    const unsigned short* Vb = Vt + (size_t)bh * 73728;
    const float* bias_b = biasT + b * 1152;

    const int srow = lane >> 2;
    const int sc8 = (lane & 3) * 8;

    bf16x8 ones;
    #pragma unroll
    for (int j = 0; j < 8; j++) ones[j] = (short)0x3F80;  // bf16 1.0

    f32x4 o[4] = {};
    f32x4 oden = {};
    const int tmax = min(1152, qrow0 + 192);

    for (int t0 = 0; t0 < tmax; t0 += 64) {
        __syncthreads();
        #pragma unroll
        for (int cc = 0; cc < 4; cc++) {
            const int c = wave * 4 + cc;
            if (c < 8) {
                const int kk = c & 1, rch = c >> 1;
                GLOAD_LDS16(Kb + (size_t)(t0 + rch * 16 + srow) * 64 + kk * 32 + sc8,
                            &Ks[kk * 2048 + rch * 512]);
            } else {
                const int c2 = c - 8, tk = c2 & 1, dch = c2 >> 1;
                GLOAD_LDS16(Vb + (size_t)(dch * 16 + srow) * 1152 + t0 + tk * 32 + sc8,
                            &Vs[tk * 2048 + dch * 512]);
            }
        }
        __syncthreads();
        if (t0 <= qrow_w + 143) {
            const bool nomask = (t0 + 63 <= 128 + qrow_w);
            float4 bt[4];
            #pragma unroll
            for (int tn = 0; tn < 4; tn++)
                bt[tn] = *(const float4*)(bias_b + t0 + tn * 16 + quad * 4);
            const int sg = qrow_w + l16;
            #pragma unroll
            for (int tn = 0; tn < 4; tn++) {
                bf16x8 kf0 = *(const bf16x8*)&Ks[0 * 2048 + (tn * 16 + l16) * 32 + quad * 8];
                bf16x8 kf1 = *(const bf16x8*)&Ks[1 * 2048 + (tn * 16 + l16) * 32 + quad * 8];
                f32x4 st = {};
                st = MFMA16(kf0, qf[0], st);
                st = MFMA16(kf1, qf[1], st);
                float p[4];
                #pragma unroll
                for (int r = 0; r < 4; r++) {
                    float e = __builtin_amdgcn_exp2f(st[r] * 0.18033688011112042f + bt[tn][r]);
                    if (!nomask) {
                        const int tg = t0 + tn * 16 + quad * 4 + r;
                        e = (tg < 128 || tg - 128 <= sg) ? e : 0.f;
                    }
                    p[r] = e;
                }
                union { ushort4 u; __hip_bfloat162 h2[2]; } pk;
                pk.h2[0] = __float22bfloat162_rn(float2{p[0], p[1]});
                pk.h2[1] = __float22bfloat162_rn(float2{p[2], p[3]});
                *(ushort4*)&Ps[wave][l16 * 72 + tn * 16 + quad * 4] = pk.u;
            }
            #pragma unroll
            for (int tk = 0; tk < 2; tk++) {
                bf16x8 pf = *(const bf16x8*)&Ps[wave][l16 * 72 + tk * 32 + quad * 8];
                oden = MFMA16(pf, ones, oden);
                #pragma unroll
                for (int dn = 0; dn < 4; dn++) {
                    bf16x8 vf = *(const bf16x8*)&Vs[tk * 2048 + (dn * 16 + l16) * 32 + quad * 8];
                    o[dn] = MFMA16(pf, vf, o[dn]);
                }
            }
        }
    }

    #pragma unroll
    for (int r = 0; r < 4; r++) {
        const float inv = 1.f / oden[r];
        const size_t orow = (size_t)(b * 1024 + qrow_w + quad * 4 + r) * 1024 + h * 64;
        #pragma unroll
        for (int dn = 0; dn < 4; dn++)
            Aout[orow + dn * 16 + l16] = f2bf(o[dn][r] * inv);
    }
}

// ---------------------------------------------------------------------------
// proj: 128x64 tiles, 512 blocks, fp32 out (m97 staging).
__global__ __launch_bounds__(256) void gemm_proj(const unsigned short* __restrict__ Abuf,
                                                 const unsigned short* __restrict__ Wpt,
                                                 const float* __restrict__ b_proj,
                                                 float* __restrict__ out) {
    __shared__ unsigned short As[128 * 32];
    __shared__ unsigned short Bs[64 * 32];
    const int tid = threadIdx.x;
    const int lane = tid & 63, wave = tid >> 6;
    const int quad = lane >> 4, l16 = lane & 15;
    const int wm = (wave & 1) * 64, wn = (wave >> 1) * 32;
    const int bm = blockIdx.x & 31, bn = blockIdx.x >> 5;
    const int crow = lane >> 2, ccol = (lane & 3) * 8;
    const unsigned short* Abase = Abuf + (size_t)(bm * 128 + crow) * 1024 + ccol;
    const unsigned short* Bbase = Wpt + (size_t)(bn * 64 + crow) * 1024 + ccol;

    f32x4 acc[4][2] = {};
    for (int k0 = 0; k0 < 1024; k0 += 32) {
        __syncthreads();
        #pragma unroll
        for (int cc = 0; cc < 3; cc++) {
            const int c = wave * 3 + cc;
            if (c < 8) GLOAD_LDS16(Abase + (size_t)(c * 16) * 1024 + k0, &As[c * 512]);
            else if (c < 12) GLOAD_LDS16(Bbase + (size_t)((c - 8) * 16) * 1024 + k0, &Bs[(c - 8) * 512]);
        }
        __syncthreads();
        bf16x8 af[4], bf[2];
        #pragma unroll
        for (int i = 0; i < 4; i++) af[i] = *(const bf16x8*)&As[(wm + i * 16 + l16) * 32 + quad * 8];
        #pragma unroll
        for (int j = 0; j < 2; j++) bf[j] = *(const bf16x8*)&Bs[(wn + j * 16 + l16) * 32 + quad * 8];
        #pragma unroll
        for (int i = 0; i < 4; i++)
            #pragma unroll
            for (int j = 0; j < 2; j++)
                acc[i][j] = MFMA16(af[i], bf[j], acc[i][j]);
    }
    float bj[2];
    #pragma unroll
    for (int j = 0; j < 2; j++) bj[j] = b_proj[bn * 64 + wn + j * 16 + l16];
    #pragma unroll
    for (int i = 0; i < 4; i++) {
        const int row = bm * 128 + wm + i * 16 + quad * 4;
        #pragma unroll
        for (int j = 0; j < 2; j++) {
            const int col = bn * 64 + wn + j * 16 + l16;
            #pragma unroll
            for (int r = 0; r < 4; r++)
                out[(size_t)(row + r) * 1024 + col] = acc[i][j][r] + bj[j];
        }
    }
}

// ---------------------------------------------------------------------------
extern "C" void kernel_launch(void* const* d_in, const int* in_sizes, int n_in,
                              void* d_out, int out_size, void* d_ws, size_t ws_size,
                              hipStream_t stream) {
    const float* x      = (const float*)d_in[0];
    const float* Mem    = (const float*)d_in[1];
    const float* Mmask  = (const float*)d_in[2];
    const float* amask  = (const float*)d_in[3];
    const float* W_attn = (const float*)d_in[4];
    const float* b_attn = (const float*)d_in[5];
    const float* W_mem  = (const float*)d_in[6];
    const float* b_mem  = (const float*)d_in[7];
    const float* W_proj = (const float*)d_in[8];
    const float* b_proj = (const float*)d_in[9];
    float* out = (float*)d_out;

    char* ws = (char*)d_ws;
    unsigned short* x_bf  = (unsigned short*)ws;  ws += (size_t)4096 * 1024 * 2;
    unsigned short* M_bf  = (unsigned short*)ws;  ws += (size_t)512 * 1024 * 2;
    unsigned short* Wat   = (unsigned short*)ws;  ws += (size_t)3072 * 1024 * 2;
    unsigned short* Wmt   = (unsigned short*)ws;  ws += (size_t)2048 * 1024 * 2;
    unsigned short* Wpt   = (unsigned short*)ws;  ws += (size_t)1024 * 1024 * 2;
    unsigned short* Qbuf  = (unsigned short*)ws;  ws += (size_t)4096 * 1024 * 2;
    unsigned short* Abuf  = (unsigned short*)ws;  ws += (size_t)4096 * 1024 * 2;
    unsigned short* Kc    = (unsigned short*)ws;  ws += (size_t)64 * 1152 * 64 * 2;
    unsigned short* Vt    = (unsigned short*)ws;  ws += (size_t)64 * 64 * 1152 * 2;
    float*          biasT = (float*)ws;           ws += (size_t)4 * 1152 * 4;
    // total ws use: ~68 MB

    prep_all<<<10771, 256, 0, stream>>>(x, Mem, x_bf, M_bf, W_attn, W_mem, W_proj,
                                        Wat, Wmt, Wpt, Mmask, amask, biasT);
    gemm_fused<<<1024, 256, 0, stream>>>(x_bf, Wat, b_attn, M_bf, Wmt, b_mem,
                                         Qbuf, Kc, Vt);
    attn_kernel<<<1024, 256, 0, stream>>>(Qbuf, Kc, Vt, biasT, Abuf);
    gemm_proj<<<512, 256, 0, stream>>>(Abuf, Wpt, b_proj, out);
}

// Round 7
// 199.410 us; speedup vs baseline: 1.4634x; 1.0501x over previous
//
#include <hip/hip_runtime.h>
#include <hip/hip_bf16.h>

// ============================================================================
// ExtraAttention on MI355X (gfx950), bf16 MFMA pipeline.
// R7: attention = uniform-work paired blocks (qg g & 31-g => 21 tiles/block
//     exactly), 1024 x 128thr (2 waves), XOR-swizzled K/V LDS (conflict-free
//     fragment reads), wave0 stages K / wave1 stages V.
// Dims: B=4 S=1024 P=128 NX=1024 H=16 dh=64 T=1152
// ============================================================================

typedef __attribute__((ext_vector_type(8))) short bf16x8;
typedef __attribute__((ext_vector_type(4))) float f32x4;

#define MFMA16(a, b, c) __builtin_amdgcn_mfma_f32_16x16x32_bf16((a), (b), (c), 0, 0, 0)

#define GLOAD_LDS16(g, l)                                                  \
    __builtin_amdgcn_global_load_lds(                                      \
        (const __attribute__((address_space(1))) void*)(const void*)(g),   \
        (__attribute__((address_space(3))) void*)(void*)(l), 16, 0, 0)

static __device__ __forceinline__ unsigned short f2bf(float f) {
    union { float f; unsigned int u; } v; v.f = f;
    unsigned int u = v.u;
    return (unsigned short)((u + 0x7fffu + ((u >> 16) & 1u)) >> 16);  // RNE
}

// ---------------------------------------------------------------------------
// Fused: fp32->bf16 converts (x, M) + 3 weight transposes + key-bias build.
static __device__ __forceinline__ void transpose_body(const float* __restrict__ W,
                                                      unsigned short* __restrict__ Wt,
                                                      int K, int N, int bx, int by,
                                                      float (*tile)[33]) {
    int n0 = bx * 32, k0 = by * 32;
    int tx = threadIdx.x & 31, ty = threadIdx.x >> 5;
    #pragma unroll
    for (int r = ty; r < 32; r += 8) tile[r][tx] = W[(size_t)(k0 + r) * N + n0 + tx];
    __syncthreads();
    #pragma unroll
    for (int r = ty; r < 32; r += 8) Wt[(size_t)(n0 + r) * K + k0 + tx] = f2bf(tile[tx][r]);
}

__global__ void prep_all(const float* __restrict__ x, const float* __restrict__ Mem,
                         unsigned short* __restrict__ x_bf, unsigned short* __restrict__ M_bf,
                         const float* __restrict__ W_attn, const float* __restrict__ W_mem,
                         const float* __restrict__ W_proj, unsigned short* __restrict__ Wat,
                         unsigned short* __restrict__ Wmt, unsigned short* __restrict__ Wpt,
                         const float* __restrict__ Mmask, const float* __restrict__ amask,
                         float* __restrict__ biasT) {
    __shared__ float tile[32][33];
    int bid = blockIdx.x;
    if (bid < 4608) {  // converts: 4608*256 threads, 4 elems each
        int i = bid * 256 + threadIdx.x;
        if (i < 1048576) {
            float4 v = ((const float4*)x)[i];
            ushort4 o; o.x = f2bf(v.x); o.y = f2bf(v.y); o.z = f2bf(v.z); o.w = f2bf(v.w);
            ((ushort4*)x_bf)[i] = o;
        } else {
            int j = i - 1048576;
            float4 v = ((const float4*)Mem)[j];
            ushort4 o; o.x = f2bf(v.x); o.y = f2bf(v.y); o.z = f2bf(v.z); o.w = f2bf(v.w);
            ((ushort4*)M_bf)[j] = o;
        }
        return;
    }
    bid -= 4608;
    if (bid < 3072) {
        transpose_body(W_attn, Wat, 1024, 3072, bid % 96, bid / 96, tile);
    } else if (bid < 5120) {
        int t = bid - 3072; transpose_body(W_mem, Wmt, 1024, 2048, t % 64, t / 64, tile);
    } else if (bid < 6144) {
        int t = bid - 5120; transpose_body(W_proj, Wpt, 1024, 1024, t % 32, t / 32, tile);
    } else {
        int i = (bid - 6144) * 256 + threadIdx.x;
        if (i < 4 * 1152) {
            int b = i / 1152, t = i % 1152;
            float v = (t < 128) ? (Mmask[b * 128 + t] - 1.f) * 10000.f
                                : amask[b * 1024 + t - 128];
            biasT[i] = v * 1.4426950408889634f;
        }
    }
}

// ---------------------------------------------------------------------------
// Fused QKV + EKV GEMM, 1024 blocks (exactly 4/CU), m97 staging (BK=32,
// global_load_lds width 16). Epilogue scatters to Qbuf / Kc[t][64] /
// Vt[64][t] (v via per-wave LDS transpose).
__global__ __launch_bounds__(256, 4) void gemm_fused(
        const unsigned short* __restrict__ x_bf, const unsigned short* __restrict__ Wat,
        const float* __restrict__ b_attn, const unsigned short* __restrict__ M_bf,
        const unsigned short* __restrict__ Wmt, const float* __restrict__ b_mem,
        unsigned short* __restrict__ Qbuf, unsigned short* __restrict__ Kc,
        unsigned short* __restrict__ Vt) {
    __shared__ char smem[34816];
    unsigned short* As = (unsigned short*)smem;             // 8 KB staging
    unsigned short* Bs = (unsigned short*)(smem + 8192);    // 8 KB staging
    const int tid = threadIdx.x;
    const int lane = tid & 63, wave = tid >> 6;
    const int quad = lane >> 4, l16 = lane & 15;
    const int crow = lane >> 2, ccol = (lane & 3) * 8;      // staging lane map
    const int bid = blockIdx.x;

    if (bid < 768) {
        // ---------------- QKV: 128x128 tile, A=x_bf[4096][1024], Bt=Wat[3072][1024]
        const int bm = bid & 31, bn = bid >> 5;             // bn 0..23
        const int wm = (wave & 1) * 64, wn = (wave >> 1) * 64;
        const unsigned short* Abase = x_bf + (size_t)(bm * 128 + crow) * 1024 + ccol;
        const unsigned short* Bbase = Wat + (size_t)(bn * 128 + crow) * 1024 + ccol;
        f32x4 acc[4][4] = {};
        for (int k0 = 0; k0 < 1024; k0 += 32) {
            __syncthreads();
            #pragma unroll
            for (int cc = 0; cc < 4; cc++) {
                const int c = wave * 4 + cc;
                if (c < 8) GLOAD_LDS16(Abase + (size_t)(c * 16) * 1024 + k0, &As[c * 512]);
                else       GLOAD_LDS16(Bbase + (size_t)((c - 8) * 16) * 1024 + k0, &Bs[(c - 8) * 512]);
            }
            __syncthreads();
            bf16x8 af[4], bf[4];
            #pragma unroll
            for (int i = 0; i < 4; i++) af[i] = *(const bf16x8*)&As[(wm + i * 16 + l16) * 32 + quad * 8];
            #pragma unroll
            for (int j = 0; j < 4; j++) bf[j] = *(const bf16x8*)&Bs[(wn + j * 16 + l16) * 32 + quad * 8];
            #pragma unroll
            for (int i = 0; i < 4; i++)
                #pragma unroll
                for (int j = 0; j < 4; j++)
                    acc[i][j] = MFMA16(af[i], bf[j], acc[i][j]);
        }
        float bj[4];
        #pragma unroll
        for (int j = 0; j < 4; j++) bj[j] = b_attn[bn * 128 + wn + j * 16 + l16];
        __syncthreads();  // smem reuse: all waves done with As/Bs
        if (bn < 8) {
            // ---- q -> Qbuf[4096][1024]
            #pragma unroll
            for (int i = 0; i < 4; i++) {
                const int row = bm * 128 + wm + i * 16 + quad * 4;
                #pragma unroll
                for (int j = 0; j < 4; j++) {
                    const int col = bn * 128 + wn + j * 16 + l16;
                    #pragma unroll
                    for (int r = 0; r < 4; r++)
                        Qbuf[(size_t)(row + r) * 1024 + col] = f2bf(acc[i][j][r] + bj[j]);
                }
            }
        } else if (bn < 16) {
            // ---- k -> Kc[bh][t=s+128][d]
            #pragma unroll
            for (int i = 0; i < 4; i++) {
                const int row = bm * 128 + wm + i * 16 + quad * 4;
                const int b = row >> 10, s = row & 1023;
                #pragma unroll
                for (int j = 0; j < 4; j++) {
                    const int c = bn * 128 + wn + j * 16 + l16 - 1024;
                    unsigned short* kd = Kc + (size_t)((b << 4) | (c >> 6)) * 73728 +
                                         (size_t)(s + 128) * 64 + (c & 63);
                    #pragma unroll
                    for (int r = 0; r < 4; r++) kd[(size_t)r * 64] = f2bf(acc[i][j][r] + bj[j]);
                }
            }
        } else {
            // ---- v -> Vt[bh][d][t] via per-wave LDS transpose (64x64, stride 68)
            unsigned short* Tw = (unsigned short*)smem + wave * 4352;
            #pragma unroll
            for (int i = 0; i < 4; i++)
                #pragma unroll
                for (int j = 0; j < 4; j++)
                    #pragma unroll
                    for (int r = 0; r < 4; r++)
                        Tw[(j * 16 + l16) * 68 + i * 16 + quad * 4 + r] = f2bf(acc[i][j][r] + bj[j]);
            const int vb = (bn - 16) * 128 + wn;            // multiple of 64
            const int h = vb >> 6;
            const int b = bm >> 3, s0 = (bm * 128 + wm) & 1023;
            unsigned short* vd = Vt + (size_t)((b << 4) | h) * 73728 +
                                 (size_t)lane * 1152 + 128 + s0;
            #pragma unroll
            for (int ch = 0; ch < 8; ch++)
                *(bf16x8*)(vd + ch * 8) = *(const bf16x8*)&Tw[lane * 68 + ch * 8];
        }
    } else {
        // ---------------- EKV: 64x64 tile, A=M_bf[512][1024], Bt=Wmt[2048][1024]
        const int t = bid - 768;
        const int bm = t >> 5, bn = t & 31;                 // bm 0..7, bn 0..31
        const int wm = (wave & 1) * 32, wn = (wave >> 1) * 32;
        const unsigned short* Abase = M_bf + (size_t)(bm * 64 + crow) * 1024 + ccol;
        const unsigned short* Bbase = Wmt + (size_t)(bn * 64 + crow) * 1024 + ccol;
        f32x4 acc[2][2] = {};
        for (int k0 = 0; k0 < 1024; k0 += 32) {
            __syncthreads();
            #pragma unroll
            for (int cc = 0; cc < 2; cc++) {
                const int c = wave * 2 + cc;
                if (c < 4) GLOAD_LDS16(Abase + (size_t)(c * 16) * 1024 + k0, &As[c * 512]);
                else       GLOAD_LDS16(Bbase + (size_t)((c - 4) * 16) * 1024 + k0, &Bs[(c - 4) * 512]);
            }
            __syncthreads();
            bf16x8 af[2], bf[2];
            #pragma unroll
            for (int i = 0; i < 2; i++) af[i] = *(const bf16x8*)&As[(wm + i * 16 + l16) * 32 + quad * 8];
            #pragma unroll
            for (int j = 0; j < 2; j++) bf[j] = *(const bf16x8*)&Bs[(wn + j * 16 + l16) * 32 + quad * 8];
            #pragma unroll
            for (int i = 0; i < 2; i++)
                #pragma unroll
                for (int j = 0; j < 2; j++)
                    acc[i][j] = MFMA16(af[i], bf[j], acc[i][j]);
        }
        float bj[2];
        #pragma unroll
        for (int j = 0; j < 2; j++) bj[j] = b_mem[bn * 64 + wn + j * 16 + l16];
        __syncthreads();
        if (bn < 16) {
            // ---- ek -> Kc[bh][t=p][d], p<128
            #pragma unroll
            for (int i = 0; i < 2; i++) {
                const int row = bm * 64 + wm + i * 16 + quad * 4;
                const int b = row >> 7, p = row & 127;
                #pragma unroll
                for (int j = 0; j < 2; j++) {
                    const int c = bn * 64 + wn + j * 16 + l16;
                    unsigned short* kd = Kc + (size_t)((b << 4) | (c >> 6)) * 73728 +
                                         (size_t)p * 64 + (c & 63);
                    #pragma unroll
                    for (int r = 0; r < 4; r++) kd[(size_t)r * 64] = f2bf(acc[i][j][r] + bj[j]);
                }
            }
        } else {
            // ---- ev -> Vt[bh][d][p] via per-wave LDS transpose (32x32, stride 36)
            unsigned short* Tw = (unsigned short*)smem + wave * 1152;
            #pragma unroll
            for (int i = 0; i < 2; i++)
                #pragma unroll
                for (int j = 0; j < 2; j++)
                    #pragma unroll
                    for (int r = 0; r < 4; r++)
                        Tw[(j * 16 + l16) * 36 + i * 16 + quad * 4 + r] = f2bf(acc[i][j][r] + bj[j]);
            const int vb = bn * 64 + wn - 1024;             // multiple of 32
            const int h = vb >> 6, d0 = vb & 63;            // d0 in {0,32}
            const int b = (bm * 64 + wm) >> 7, p0 = (bm * 64 + wm) & 127;
            const int lc = lane >> 1, half = lane & 1;
            unsigned short* vd = Vt + (size_t)((b << 4) | h) * 73728 +
                                 (size_t)(d0 + lc) * 1152 + p0 + half * 16;
            #pragma unroll
            for (int ch = 0; ch < 2; ch++)
                *(bf16x8*)(vd + ch * 8) = *(const bf16x8*)&Tw[lc * 36 + half * 16 + ch * 8];
        }
    }
}

// ---------------------------------------------------------------------------
// Attention v7: 1024 blocks x 128 thr (2 waves). Block = (bh, pair p):
// processes q-group g=p (32 rows) then g'=31-p -> exactly 21 K/V tiles per
// block (uniform makespan). Wave owns 16 q-rows. Per 64-t tile: wave0 stages
// K, wave1 stages V into XOR-swizzled LDS ([64 rows][64 elems], 16B block c
// stored at c^(row&7)) -> conflict-free b128 fragment reads. den via
// MFMA(P, ones). XCD swizzle keeps each bh's K/V in its home L2.
__global__ __launch_bounds__(128) void attn_kernel(const unsigned short* __restrict__ Qbuf,
                                                   const unsigned short* __restrict__ Kc,
                                                   const unsigned short* __restrict__ Vt,
                                                   const float* __restrict__ biasT,
                                                   unsigned short* __restrict__ Aout) {
    __shared__ unsigned short Ks[64 * 64];     // swizzled [t][64 k-elems]
    __shared__ unsigned short Vs[64 * 64];     // swizzled [d][64 t-elems]
    __shared__ unsigned short Ps[2][16 * 72];  // per-wave P tile [s][t]
    const int tid = threadIdx.x;
    const int lane = tid & 63, wave = tid >> 6;
    const int quad = lane >> 4, l16 = lane & 15;
    const int blk = blockIdx.x;                 // 1024 = 8 xcd x 8 bh x 16 pair
    const int xcd = blk & 7, idx = blk >> 3;
    const int bh = xcd * 8 + (idx & 7);
    const int pair = idx >> 3;                  // 0..15
    const int h = bh & 15, b = bh >> 4;

    const unsigned short* Kb = Kc + (size_t)bh * 73728;
    const unsigned short* Vb = Vt + (size_t)bh * 73728;
    const float* bias_b = biasT + b * 1152;

    // staging lane map (chunk-independent because chunks are 8-row aligned)
    const int srow = lane >> 3;                        // row within 8-row chunk
    const int scol = ((lane & 7) ^ srow) * 8;          // swizzled 16B block
    const int rswz = l16 & 7;                          // read-side swizzle key

    bf16x8 ones;
    #pragma unroll
    for (int j = 0; j < 8; j++) ones[j] = (short)0x3F80;  // bf16 1.0

    #pragma unroll
    for (int phase = 0; phase < 2; phase++) {
        const int qg = phase ? (31 - pair) : pair;     // uniform: tiles(g)+tiles(31-g)=21
        const int qrow0 = qg * 32;
        const int qrow_w = qrow0 + wave * 16;

        bf16x8 qf[2];
        #pragma unroll
        for (int k2 = 0; k2 < 2; k2++)
            qf[k2] = *(const bf16x8*)(Qbuf + (size_t)(b * 1024 + qrow_w + l16) * 1024 +
                                      h * 64 + k2 * 32 + quad * 8);

        f32x4 o[4] = {};
        f32x4 oden = {};
        const int tmax = min(1152, ((qrow0 + 223) >> 6) << 6);

        for (int t0 = 0; t0 < tmax; t0 += 64) {
            __syncthreads();  // all waves done reading previous tile
            if (wave == 0) {  // stage K rows t0..t0+63
                const unsigned short* g = Kb + (size_t)(t0 + srow) * 64 + scol;
                #pragma unroll
                for (int ch = 0; ch < 8; ch++)
                    GLOAD_LDS16(g + (size_t)(ch * 8) * 64, &Ks[ch * 512]);
            } else {          // stage V rows d=0..63, cols t0..t0+63
                const unsigned short* g = Vb + (size_t)srow * 1152 + t0 + scol;
                #pragma unroll
                for (int ch = 0; ch < 8; ch++)
                    GLOAD_LDS16(g + (size_t)(ch * 8) * 1152, &Vs[ch * 512]);
            }
            __syncthreads();  // drains vmcnt -> staged tile visible
            if (t0 <= qrow_w + 143) {
                const bool nomask = (t0 + 63 <= 128 + qrow_w);
                float4 bt[4];
                #pragma unroll
                for (int tn = 0; tn < 4; tn++)
                    bt[tn] = *(const float4*)(bias_b + t0 + tn * 16 + quad * 4);
                const int sg = qrow_w + l16;
                #pragma unroll
                for (int tn = 0; tn < 4; tn++) {
                    bf16x8 kf0 = *(const bf16x8*)&Ks[(tn * 16 + l16) * 64 + (quad ^ rswz) * 8];
                    bf16x8 kf1 = *(const bf16x8*)&Ks[(tn * 16 + l16) * 64 + ((quad + 4) ^ rswz) * 8];
                    f32x4 st = {};
                    st = MFMA16(kf0, qf[0], st);
                    st = MFMA16(kf1, qf[1], st);
                    float p[4];
                    #pragma unroll
                    for (int r = 0; r < 4; r++) {
                        float e = __builtin_amdgcn_exp2f(st[r] * 0.18033688011112042f + bt[tn][r]);
                        if (!nomask) {
                            const int tg = t0 + tn * 16 + quad * 4 + r;
                            e = (tg < 128 || tg - 128 <= sg) ? e : 0.f;
                        }
                        p[r] = e;
                    }
                    union { ushort4 u; __hip_bfloat162 h2[2]; } pk;
                    pk.h2[0] = __float22bfloat162_rn(float2{p[0], p[1]});
                    pk.h2[1] = __float22bfloat162_rn(float2{p[2], p[3]});
                    *(ushort4*)&Ps[wave][l16 * 72 + tn * 16 + quad * 4] = pk.u;
                }
                #pragma unroll
                for (int tk = 0; tk < 2; tk++) {
                    bf16x8 pf = *(const bf16x8*)&Ps[wave][l16 * 72 + tk * 32 + quad * 8];
                    oden = MFMA16(pf, ones, oden);
                    #pragma unroll
                    for (int dn = 0; dn < 4; dn++) {
                        bf16x8 vf = *(const bf16x8*)&Vs[(dn * 16 + l16) * 64 +
                                                        ((tk * 4 + quad) ^ rswz) * 8];
                        o[dn] = MFMA16(pf, vf, o[dn]);
                    }
                }
            }
        }

        // epilogue: o C-layout row s = quad*4+r, col d = dn*16+l16
        #pragma unroll
        for (int r = 0; r < 4; r++) {
            const float inv = 1.f / oden[r];
            const size_t orow = (size_t)(b * 1024 + qrow_w + quad * 4 + r) * 1024 + h * 64;
            #pragma unroll
            for (int dn = 0; dn < 4; dn++)
                Aout[orow + dn * 16 + l16] = f2bf(o[dn][r] * inv);
        }
    }
}

// ---------------------------------------------------------------------------
// proj: 128x64 tiles, 512 blocks, fp32 out (m97 staging).
__global__ __launch_bounds__(256) void gemm_proj(const unsigned short* __restrict__ Abuf,
                                                 const unsigned short* __restrict__ Wpt,
                                                 const float* __restrict__ b_proj,
                                                 float* __restrict__ out) {
    __shared__ unsigned short As[128 * 32];
    __shared__ unsigned short Bs[64 * 32];
    const int tid = threadIdx.x;
    const int lane = tid & 63, wave = tid >> 6;
    const int quad = lane >> 4, l16 = lane & 15;
    const int wm = (wave & 1) * 64, wn = (wave >> 1) * 32;
    const int bm = blockIdx.x & 31, bn = blockIdx.x >> 5;
    const int crow = lane >> 2, ccol = (lane & 3) * 8;
    const unsigned short* Abase = Abuf + (size_t)(bm * 128 + crow) * 1024 + ccol;
    const unsigned short* Bbase = Wpt + (size_t)(bn * 64 + crow) * 1024 + ccol;

    f32x4 acc[4][2] = {};
    for (int k0 = 0; k0 < 1024; k0 += 32) {
        __syncthreads();
        #pragma unroll
        for (int cc = 0; cc < 3; cc++) {
            const int c = wave * 3 + cc;
            if (c < 8) GLOAD_LDS16(Abase + (size_t)(c * 16) * 1024 + k0, &As[c * 512]);
            else if (c < 12) GLOAD_LDS16(Bbase + (size_t)((c - 8) * 16) * 1024 + k0, &Bs[(c - 8) * 512]);
        }
        __syncthreads();
        bf16x8 af[4], bf[2];
        #pragma unroll
        for (int i = 0; i < 4; i++) af[i] = *(const bf16x8*)&As[(wm + i * 16 + l16) * 32 + quad * 8];
        #pragma unroll
        for (int j = 0; j < 2; j++) bf[j] = *(const bf16x8*)&Bs[(wn + j * 16 + l16) * 32 + quad * 8];
        #pragma unroll
        for (int i = 0; i < 4; i++)
            #pragma unroll
            for (int j = 0; j < 2; j++)
                acc[i][j] = MFMA16(af[i], bf[j], acc[i][j]);
    }
    float bj[2];
    #pragma unroll
    for (int j = 0; j < 2; j++) bj[j] = b_proj[bn * 64 + wn + j * 16 + l16];
    #pragma unroll
    for (int i = 0; i < 4; i++) {
        const int row = bm * 128 + wm + i * 16 + quad * 4;
        #pragma unroll
        for (int j = 0; j < 2; j++) {
            const int col = bn * 64 + wn + j * 16 + l16;
            #pragma unroll
            for (int r = 0; r < 4; r++)
                out[(size_t)(row + r) * 1024 + col] = acc[i][j][r] + bj[j];
        }
    }
}

// ---------------------------------------------------------------------------
extern "C" void kernel_launch(void* const* d_in, const int* in_sizes, int n_in,
                              void* d_out, int out_size, void* d_ws, size_t ws_size,
                              hipStream_t stream) {
    const float* x      = (const float*)d_in[0];
    const float* Mem    = (const float*)d_in[1];
    const float* Mmask  = (const float*)d_in[2];
    const float* amask  = (const float*)d_in[3];
    const float* W_attn = (const float*)d_in[4];
    const float* b_attn = (const float*)d_in[5];
    const float* W_mem  = (const float*)d_in[6];
    const float* b_mem  = (const float*)d_in[7];
    const float* W_proj = (const float*)d_in[8];
    const float* b_proj = (const float*)d_in[9];
    float* out = (float*)d_out;

    char* ws = (char*)d_ws;
    unsigned short* x_bf  = (unsigned short*)ws;  ws += (size_t)4096 * 1024 * 2;
    unsigned short* M_bf  = (unsigned short*)ws;  ws += (size_t)512 * 1024 * 2;
    unsigned short* Wat   = (unsigned short*)ws;  ws += (size_t)3072 * 1024 * 2;
    unsigned short* Wmt   = (unsigned short*)ws;  ws += (size_t)2048 * 1024 * 2;
    unsigned short* Wpt   = (unsigned short*)ws;  ws += (size_t)1024 * 1024 * 2;
    unsigned short* Qbuf  = (unsigned short*)ws;  ws += (size_t)4096 * 1024 * 2;
    unsigned short* Abuf  = (unsigned short*)ws;  ws += (size_t)4096 * 1024 * 2;
    unsigned short* Kc    = (unsigned short*)ws;  ws += (size_t)64 * 1152 * 64 * 2;
    unsigned short* Vt    = (unsigned short*)ws;  ws += (size_t)64 * 64 * 1152 * 2;
    float*          biasT = (float*)ws;           ws += (size_t)4 * 1152 * 4;
    // total ws use: ~68 MB

    prep_all<<<10771, 256, 0, stream>>>(x, Mem, x_bf, M_bf, W_attn, W_mem, W_proj,
                                        Wat, Wmt, Wpt, Mmask, amask, biasT);
    gemm_fused<<<1024, 256, 0, stream>>>(x_bf, Wat, b_attn, M_bf, Wmt, b_mem,
                                         Qbuf, Kc, Vt);
    attn_kernel<<<1024, 128, 0, stream>>>(Qbuf, Kc, Vt, biasT, Abuf);
    gemm_proj<<<512, 256, 0, stream>>>(Abuf, Wpt, b_proj, out);
}